// Round 9
// baseline (801.263 us; speedup 1.0000x reference)
//
#include <hip/hip_runtime.h>
#include <math.h>

#define TPB 256

// problem dims
#define B_  32
#define L_  2048
#define C_  32
#define PL_ 16
#define P_  128
#define D_  64
#define HE_ 256
#define HD_ 256
#define K_  512
#define N_  1024      // B*C
#define M_  131072    // N_*P_

#define EPS_  1e-5f
#define BETA_ 0.25f
#define CW_   0.2f

// output offsets (floats). order: loss_total, rec_loss, z_q_st, r, indices, perplexity
#define OUT_LOSS 0
#define OUT_REC  1
#define OUT_ZQ   2
#define OUT_R    8388610      // 2 + M_*D_
#define OUT_IDX  10485762     // OUT_R + B_*L_*C_
#define OUT_PERP 10616834     // OUT_IDX + M_

// workspace offsets (floats)
#define WS_MEAN   0
#define WS_STD    1024
#define WS_QT     2048        // WqT [64 t][64 j]
#define WS_KT     6144        // WkT
#define WS_VT     10240       // WvT
#define WS_E2     34816
#define WS_COUNTS 35328
#define WS_CPART  35840       // 1024 entries, ends at 36864
#define WS_H0     36864
#define WS_H1     8425472     // WS_H0 + M_*D_  (AO; dead after k_woffn -> RPART scratch)
#define WS_RPART  WS_H1

// ---------------- prep: transposes (Wq, Wk, Wv) + codebook e2 ----------------
__global__ void k_prep(const float* __restrict__ Wq, const float* __restrict__ Wk,
                       const float* __restrict__ Wv,
                       const float* __restrict__ cb, float* __restrict__ ws) {
    int g = blockIdx.x * TPB + threadIdx.x;
    if (g < 4096) { int t = g >> 6, j = g & 63; ws[WS_QT + g] = Wq[j * D_ + t]; }
    else if (g < 8192) { int g2 = g - 4096; int t = g2 >> 6, j = g2 & 63; ws[WS_KT + g2] = Wk[j * D_ + t]; }
    else if (g < 12288) { int g2 = g - 8192; int t = g2 >> 6, j = g2 & 63; ws[WS_VT + g2] = Wv[j * D_ + t]; }
    if (g < K_) {
        float s = 0.f;
        for (int j = 0; j < D_; j++) { float v = cb[g * D_ + j]; s += v * v; }
        ws[WS_E2 + g] = s;
    }
}

// ---------------- RevIN stats over time dim ----------------
__global__ void k_stats(const float* __restrict__ x, float* __restrict__ ws) {
    int bc = blockIdx.x;
    int b = bc >> 5, c = bc & 31;
    const float* xp = x + (size_t)b * L_ * C_ + c;
    float s = 0.f, s2 = 0.f;
    for (int l = threadIdx.x; l < L_; l += TPB) { float v = xp[(size_t)l * C_]; s += v; s2 += v * v; }
    __shared__ float sh[TPB], sh2[TPB];
    sh[threadIdx.x] = s; sh2[threadIdx.x] = s2; __syncthreads();
    for (int o2 = 128; o2 > 0; o2 >>= 1) {
        if (threadIdx.x < o2) { sh[threadIdx.x] += sh[threadIdx.x + o2]; sh2[threadIdx.x] += sh2[threadIdx.x + o2]; }
        __syncthreads();
    }
    if (threadIdx.x == 0) {
        float m = sh[0] / (float)L_;
        float var = sh2[0] / (float)L_ - m * m;
        ws[WS_MEAN + bc] = m;
        ws[WS_STD + bc] = sqrtf(var + EPS_);
    }
}

// ---------------- patchify + input embedding ----------------
__global__ __launch_bounds__(TPB) void k_embed(
    const float* __restrict__ x, const float* __restrict__ rw, const float* __restrict__ rb,
    const float* __restrict__ inpW, const float* __restrict__ inpb, float* __restrict__ ws) {
    int idx = blockIdx.x * TPB + threadIdx.x;          // < M_*D_
    int row = idx >> 6, d = idx & 63;
    int n = row >> 7, p = row & 127;
    int b = n >> 5, c = n & 31;
    float m = ws[WS_MEAN + n], sd = ws[WS_STD + n];
    float w = rw[c], bb = rb[c];
    const float* xp = x + (size_t)b * L_ * C_ + (size_t)p * PL_ * C_ + c;
    float acc = inpb[d];
#pragma unroll
    for (int j = 0; j < PL_; j++) {
        float xv = xp[(size_t)j * C_];
        float xn = (xv - m) / sd * w + bb;
        acc += xn * inpW[j * D_ + d];
    }
    ws[WS_H0 + (size_t)idx] = acc;
}

// ---------------- attention v9: reg K/V + LDS reuse + max-free single-pass softmax ----------------
#define HSS  68         // hs row stride
#define KH_  0          // [128][16] floats, overwrites hs region after barrier
#define VH_  2048
#define SMF  8704       // 128*68 floats = 34816 bytes -> 4 blocks/CU

__global__ __launch_bounds__(TPB) void k_attn(
    float* __restrict__ ws,
    const float* __restrict__ bq, const float* __restrict__ bk, const float* __restrict__ bv) {
    __shared__ float sm[SMF];
    const int tid = threadIdx.x;
    const int n = blockIdx.x >> 2, hh = blockIdx.x & 3;
    const float* h0 = ws + WS_H0 + (size_t)n * (P_ * D_);
    float* agl = ws + WS_H1 + (size_t)n * (P_ * D_);   // AO output

    // stage hs [r][HSS]
    {
        const float4* h04 = (const float4*)h0;
#pragma unroll
        for (int it = 0; it < 8; ++it) {
            int e = tid + it * 256;
            int r = e >> 4, j4 = e & 15;
            *(float4*)(sm + r * HSS + j4 * 4) = h04[e];
        }
    }
    __syncthreads();

    const int t_ = tid & 15, ib = tid >> 4;
    const float4* WqT4 = (const float4*)(ws + WS_QT);
    const float4* WkT4 = (const float4*)(ws + WS_KT);
    const float4* WvT4 = (const float4*)(ws + WS_VT);

    float kreg[8], vreg[8];
    // ---- K into regs: thread owns dim t_, rows ib+16*it ----
    {
        float4 wreg[16];
        const float4* kr = WkT4 + (size_t)(hh * 16 + t_) * 16;
#pragma unroll
        for (int j4 = 0; j4 < 16; j4++) wreg[j4] = kr[j4];
        float bb = bk[hh * 16 + t_];
#pragma unroll
        for (int it = 0; it < 8; it++) {
            int i2 = ib + it * 16;
            const float4* hr = (const float4*)(sm + i2 * HSS);
            float acc = bb;
#pragma unroll
            for (int j4 = 0; j4 < 16; j4++) {
                float4 h4 = hr[j4], w4 = wreg[j4];
                acc += h4.x * w4.x + h4.y * w4.y + h4.z * w4.z + h4.w * w4.w;
            }
            kreg[it] = acc;
        }
    }
    // ---- V into regs ----
    {
        float4 wreg[16];
        const float4* vr = WvT4 + (size_t)(hh * 16 + t_) * 16;
#pragma unroll
        for (int j4 = 0; j4 < 16; j4++) wreg[j4] = vr[j4];
        float bb = bv[hh * 16 + t_];
#pragma unroll
        for (int it = 0; it < 8; it++) {
            int i2 = ib + it * 16;
            const float4* hr = (const float4*)(sm + i2 * HSS);
            float acc = bb;
#pragma unroll
            for (int j4 = 0; j4 < 16; j4++) {
                float4 h4 = hr[j4], w4 = wreg[j4];
                acc += h4.x * w4.x + h4.y * w4.y + h4.z * w4.z + h4.w * w4.w;
            }
            vreg[it] = acc;
        }
    }
    // ---- q: pair (row i, half) computes 8 dims from LDS hs, exchange -> full q ----
    const int i = tid >> 1, half = tid & 1;
    float q0[8], q1[8];
    {
        float4 hreg[16];
        const float4* hr = (const float4*)(sm + i * HSS);
#pragma unroll
        for (int j4 = 0; j4 < 16; j4++) hreg[j4] = hr[j4];
        float qh[8];
#pragma unroll
        for (int u = 0; u < 8; u++) {
            const float4* wr = WqT4 + (size_t)(hh * 16 + half * 8 + u) * 16;
            float acc = bq[hh * 16 + half * 8 + u];
#pragma unroll
            for (int j4 = 0; j4 < 16; j4++) {
                float4 w4 = wr[j4];
                acc += hreg[j4].x * w4.x + hreg[j4].y * w4.y + hreg[j4].z * w4.z + hreg[j4].w * w4.w;
            }
            qh[u] = acc;
        }
#pragma unroll
        for (int u = 0; u < 8; u++) {
            float oth = __shfl_xor(qh[u], 1);
            q0[u] = half ? oth : qh[u];
            q1[u] = half ? qh[u] : oth;
        }
    }
    __syncthreads();   // all hs reads done -> region reusable
    // ---- write K/V tiles over dead hs region ----
#pragma unroll
    for (int it = 0; it < 8; it++) {
        int i2 = ib + it * 16;
        sm[KH_ + i2 * 16 + t_] = kreg[it];
        sm[VH_ + i2 * 16 + t_] = vreg[it];
    }
    __syncthreads();
    // ---- max-free single-pass softmax over parity keys ----
    float S = 0.f;
    float o[16];
#pragma unroll
    for (int u = 0; u < 16; u++) o[u] = 0.f;
    const float4* kh4 = (const float4*)(sm + KH_);
    const float4* vh4 = (const float4*)(sm + VH_);
#pragma unroll 4
    for (int m2 = 0; m2 < 64; m2++) {
        int m = m2 * 2 + half;
        float4 a0 = kh4[m * 4 + 0], a1 = kh4[m * 4 + 1], a2 = kh4[m * 4 + 2], a3 = kh4[m * 4 + 3];
        float sp = q0[0] * a0.x + q0[1] * a0.y + q0[2] * a0.z + q0[3] * a0.w
                 + q0[4] * a1.x + q0[5] * a1.y + q0[6] * a1.z + q0[7] * a1.w
                 + q1[0] * a2.x + q1[1] * a2.y + q1[2] * a2.z + q1[3] * a2.w
                 + q1[4] * a3.x + q1[5] * a3.y + q1[6] * a3.z + q1[7] * a3.w;
        float p = __expf(sp * 0.25f);   // scores tiny (|s|<<1): exp w/o max-shift is exact softmax
        S += p;
        float4 v0 = vh4[m * 4 + 0], v1 = vh4[m * 4 + 1], v2 = vh4[m * 4 + 2], v3 = vh4[m * 4 + 3];
        o[0] += p * v0.x; o[1] += p * v0.y; o[2] += p * v0.z; o[3] += p * v0.w;
        o[4] += p * v1.x; o[5] += p * v1.y; o[6] += p * v1.z; o[7] += p * v1.w;
        o[8] += p * v2.x; o[9] += p * v2.y; o[10] += p * v2.z; o[11] += p * v2.w;
        o[12] += p * v3.x; o[13] += p * v3.y; o[14] += p * v3.z; o[15] += p * v3.w;
    }
    // ---- merge pair (pure add) ----
    {
        S += __shfl_xor(S, 1);
        float inv = 1.f / S;
        float wv[8];
#pragma unroll
        for (int u = 0; u < 8; u++) {
            float lo = o[u] + __shfl_xor(o[u], 1);
            float hi = o[8 + u] + __shfl_xor(o[8 + u], 1);
            wv[u] = (half ? hi : lo) * inv;
        }
        float4 r0, r1;
        r0.x = wv[0]; r0.y = wv[1]; r0.z = wv[2]; r0.w = wv[3];
        r1.x = wv[4]; r1.y = wv[5]; r1.z = wv[6]; r1.w = wv[7];
        float4* ap4 = (float4*)(agl + (size_t)i * D_ + hh * 16 + half * 8);
        ap4[0] = r0; ap4[1] = r1;
    }
}

// ---------------- fused Wo+LN1+FFN+LN2: AO -> z, no h1 round-trip ----------------
#define FHS  68

__global__ __launch_bounds__(TPB) void k_woffn(
    float* __restrict__ ws, const float* __restrict__ Wo, const float* __restrict__ bo,
    const float* __restrict__ g1, const float* __restrict__ b1,
    const float* __restrict__ fW1, const float* __restrict__ fb1,
    const float* __restrict__ fW2, const float* __restrict__ fb2,
    const float* __restrict__ g2, const float* __restrict__ b2) {
    __shared__ float bufA[64][FHS];   // aoT in phase A, Hc in phase B
    __shared__ float hT[64][FHS];     // h1 transposed [d][row]
    const int tid = threadIdx.x;
    const int row0 = blockIdx.x * 64;
    const float* aog = ws + WS_H1 + (size_t)row0 * D_;

    // stage aoT
    {
        const float4* ao4 = (const float4*)aog;
#pragma unroll
        for (int it = 0; it < 4; ++it) {
            int e = tid + it * 256;
            int r = e >> 4, j4 = e & 15;
            float4 v = ao4[e];
            bufA[j4 * 4 + 0][r] = v.x; bufA[j4 * 4 + 1][r] = v.y;
            bufA[j4 * 4 + 2][r] = v.z; bufA[j4 * 4 + 3][r] = v.w;
        }
    }
    const int ty = tid >> 4, tx = tid & 15;
    // ---- phase A: Wo GEMM ----
    float acc[4][4];
    {
        float4 bb = ((const float4*)bo)[tx];
#pragma unroll
        for (int r = 0; r < 4; r++) { acc[r][0] = bb.x; acc[r][1] = bb.y; acc[r][2] = bb.z; acc[r][3] = bb.w; }
    }
    __syncthreads();
    const float4* Wo4 = (const float4*)Wo;
#pragma unroll 4
    for (int j = 0; j < 64; ++j) {
        float4 a = *(const float4*)&bufA[j][ty * 4];
        float4 w = Wo4[j * 16 + tx];
        float ar[4] = {a.x, a.y, a.z, a.w}, wr[4] = {w.x, w.y, w.z, w.w};
#pragma unroll
        for (int r = 0; r < 4; r++)
#pragma unroll
            for (int c = 0; c < 4; c++) acc[r][c] += ar[r] * wr[c];
    }
    // residual + LN1 -> h1v (kept in regs)
    float h1v[4][4];
    {
        const float4* h04 = (const float4*)(ws + WS_H0 + (size_t)row0 * D_);
        float4 gg = ((const float4*)g1)[tx], bbn = ((const float4*)b1)[tx];
#pragma unroll
        for (int r = 0; r < 4; r++) {
            float4 res = h04[(ty * 4 + r) * 16 + tx];
            acc[r][0] += res.x; acc[r][1] += res.y; acc[r][2] += res.z; acc[r][3] += res.w;
            float s = acc[r][0] + acc[r][1] + acc[r][2] + acc[r][3];
            s += __shfl_xor(s, 1); s += __shfl_xor(s, 2); s += __shfl_xor(s, 4); s += __shfl_xor(s, 8);
            float mean_ = s * (1.f / 64.f);
            float vv = 0.f;
#pragma unroll
            for (int c = 0; c < 4; c++) { float d_ = acc[r][c] - mean_; vv += d_ * d_; }
            vv += __shfl_xor(vv, 1); vv += __shfl_xor(vv, 2); vv += __shfl_xor(vv, 4); vv += __shfl_xor(vv, 8);
            float rstd = 1.f / sqrtf(vv * (1.f / 64.f) + EPS_);
            h1v[r][0] = (acc[r][0] - mean_) * rstd * gg.x + bbn.x;
            h1v[r][1] = (acc[r][1] - mean_) * rstd * gg.y + bbn.y;
            h1v[r][2] = (acc[r][2] - mean_) * rstd * gg.z + bbn.z;
            h1v[r][3] = (acc[r][3] - mean_) * rstd * gg.w + bbn.w;
        }
    }
    // scatter h1 into hT[d][row]
#pragma unroll
    for (int r = 0; r < 4; r++)
#pragma unroll
        for (int c = 0; c < 4; c++) hT[tx * 4 + c][ty * 4 + r] = h1v[r][c];
    // ---- phase B: FFN GEMMs (Hc aliases bufA) ----
    const float4* W14 = (const float4*)fW1;
    const float4* W24 = (const float4*)fW2;
    float outv[4][4];
    {
        float4 bb = ((const float4*)fb2)[tx];
#pragma unroll
        for (int r = 0; r < 4; r++) { outv[r][0] = bb.x; outv[r][1] = bb.y; outv[r][2] = bb.z; outv[r][3] = bb.w; }
    }
    __syncthreads();   // hT ready; all aoT reads done -> bufA reusable

    for (int tc = 0; tc < 4; ++tc) {
        float a2[4][4];
        {
            float4 bb1 = ((const float4*)fb1)[tc * 16 + tx];
#pragma unroll
            for (int r = 0; r < 4; r++) { a2[r][0] = bb1.x; a2[r][1] = bb1.y; a2[r][2] = bb1.z; a2[r][3] = bb1.w; }
        }
#pragma unroll 4
        for (int j = 0; j < 64; ++j) {
            float4 a = *(const float4*)&hT[j][ty * 4];
            float4 w = W14[j * 64 + tc * 16 + tx];
            float ar[4] = {a.x, a.y, a.z, a.w}, wr[4] = {w.x, w.y, w.z, w.w};
#pragma unroll
            for (int r = 0; r < 4; r++)
#pragma unroll
                for (int c = 0; c < 4; c++) a2[r][c] += ar[r] * wr[c];
        }
        __syncthreads();   // prev Hc reads done
#pragma unroll
        for (int r = 0; r < 4; r++)
#pragma unroll
            for (int c = 0; c < 4; c++) bufA[tx * 4 + c][ty * 4 + r] = fmaxf(a2[r][c], 0.f);
        __syncthreads();
#pragma unroll 4
        for (int h = 0; h < 64; ++h) {
            float4 a = *(const float4*)&bufA[h][ty * 4];
            float4 w = W24[(tc * 64 + h) * 16 + tx];
            float ar[4] = {a.x, a.y, a.z, a.w}, wr[4] = {w.x, w.y, w.z, w.w};
#pragma unroll
            for (int r = 0; r < 4; r++)
#pragma unroll
                for (int c = 0; c < 4; c++) outv[r][c] += ar[r] * wr[c];
        }
    }
    // residual (h1v) + LN2 -> z
    {
        float4 gg = ((const float4*)g2)[tx], bb = ((const float4*)b2)[tx];
        float4* zp = (float4*)(ws + WS_H0 + (size_t)row0 * D_);
#pragma unroll
        for (int r = 0; r < 4; r++) {
            outv[r][0] += h1v[r][0]; outv[r][1] += h1v[r][1];
            outv[r][2] += h1v[r][2]; outv[r][3] += h1v[r][3];
            float s = outv[r][0] + outv[r][1] + outv[r][2] + outv[r][3];
            s += __shfl_xor(s, 1); s += __shfl_xor(s, 2); s += __shfl_xor(s, 4); s += __shfl_xor(s, 8);
            float mean_ = s * (1.f / 64.f);
            float vv = 0.f;
#pragma unroll
            for (int c = 0; c < 4; c++) { float d_ = outv[r][c] - mean_; vv += d_ * d_; }
            vv += __shfl_xor(vv, 1); vv += __shfl_xor(vv, 2); vv += __shfl_xor(vv, 4); vv += __shfl_xor(vv, 8);
            float rstd = 1.f / sqrtf(vv * (1.f / 64.f) + EPS_);
            float4 z;
            z.x = (outv[r][0] - mean_) * rstd * gg.x + bb.x;
            z.y = (outv[r][1] - mean_) * rstd * gg.y + bb.y;
            z.z = (outv[r][2] - mean_) * rstd * gg.z + bb.z;
            z.w = (outv[r][3] - mean_) * rstd * gg.w + bb.w;
            zp[(ty * 4 + r) * 16 + tx] = z;
        }
    }
}

// ---------------- quantizer: LDS-tiled register-blocked distance GEMM ----------------
#define QROWS 128
#define QKT   64
#define ZTS   132
#define CBS   68

__global__ __launch_bounds__(TPB) void k_quant(
    float* __restrict__ ws, const float* __restrict__ cb, float* __restrict__ out) {
    __shared__ float zT[64][ZTS];
    __shared__ float cbT[64][CBS];
    __shared__ float z2s[QROWS];
    __shared__ float e2t[QKT];
    __shared__ int   ridx[QROWS];
    __shared__ float red[TPB];

    const int tid = threadIdx.x;
    const int row0 = blockIdx.x * QROWS;
    const float* zg = ws + WS_H0 + (size_t)row0 * D_;
    const float4* zg4 = (const float4*)zg;
    const float4* cbg4 = (const float4*)cb;

    {
        int j4 = tid >> 4;
#pragma unroll
        for (int it = 0; it < 8; ++it) {
            int r = (tid & 15) + it * 16;
            float4 v = zg4[r * 16 + j4];
            zT[j4 * 4 + 0][r] = v.x; zT[j4 * 4 + 1][r] = v.y;
            zT[j4 * 4 + 2][r] = v.z; zT[j4 * 4 + 3][r] = v.w;
        }
    }
    if (tid < QROWS) {
        const float4* zr = (const float4*)(zg + (size_t)tid * D_);
        float s = 0.f;
#pragma unroll
        for (int j = 0; j < 16; j++) { float4 v = zr[j]; s += v.x * v.x + v.y * v.y + v.z * v.z + v.w * v.w; }
        z2s[tid] = s;
    }

    const int ty = tid >> 4, tx = tid & 15;
    float best[8]; int bidx[8];
#pragma unroll
    for (int u = 0; u < 8; u++) { best[u] = 3.4e38f; bidx[u] = 0; }

    for (int t = 0; t < K_ / QKT; ++t) {
        const int k0 = t * QKT;
        __syncthreads();
        {
            int j4 = tid >> 4;
#pragma unroll
            for (int it = 0; it < 4; ++it) {
                int kk = (tid & 15) + it * 16;
                float4 v = cbg4[(size_t)(k0 + kk) * 16 + j4];
                cbT[j4 * 4 + 0][kk] = v.x; cbT[j4 * 4 + 1][kk] = v.y;
                cbT[j4 * 4 + 2][kk] = v.z; cbT[j4 * 4 + 3][kk] = v.w;
            }
        }
        if (tid < QKT) e2t[tid] = ws[WS_E2 + k0 + tid];
        __syncthreads();

        float acc[8][4];
#pragma unroll
        for (int u = 0; u < 8; u++)
#pragma unroll
            for (int c = 0; c < 4; c++) acc[u][c] = 0.f;

        for (int j = 0; j < 64; ++j) {
            float4 a0 = *(const float4*)&zT[j][ty * 8];
            float4 a1 = *(const float4*)&zT[j][ty * 8 + 4];
            float4 b0 = *(const float4*)&cbT[j][tx * 4];
            float ar[8] = {a0.x, a0.y, a0.z, a0.w, a1.x, a1.y, a1.z, a1.w};
            float br[4] = {b0.x, b0.y, b0.z, b0.w};
#pragma unroll
            for (int u = 0; u < 8; u++)
#pragma unroll
                for (int c = 0; c < 4; c++) acc[u][c] += ar[u] * br[c];
        }

#pragma unroll
        for (int u = 0; u < 8; u++) {
            float z2v = z2s[ty * 8 + u];
#pragma unroll
            for (int c = 0; c < 4; c++) {
                float dist = (z2v + e2t[tx * 4 + c]) - 2.f * acc[u][c];
                int kidx = k0 + tx * 4 + c;
                if (dist < best[u]) { best[u] = dist; bidx[u] = kidx; }
            }
        }
    }

#pragma unroll
    for (int m = 1; m <= 8; m <<= 1) {
#pragma unroll
        for (int u = 0; u < 8; u++) {
            float ob = __shfl_xor(best[u], m, 64);
            int oi = __shfl_xor(bidx[u], m, 64);
            if (ob < best[u] || (ob == best[u] && oi < bidx[u])) { best[u] = ob; bidx[u] = oi; }
        }
    }
    if (tx == 0) {
#pragma unroll
        for (int u = 0; u < 8; u++) ridx[ty * 8 + u] = bidx[u];
    }
    __syncthreads();

    if (tid < QROWS) {
        int bi = ridx[tid];
        out[OUT_IDX + row0 + tid] = (float)bi;
        atomicAdd((unsigned int*)ws + WS_COUNTS + bi, 1u);
    }
    {
        int r = tid >> 1, half = tid & 1;
        int bi = ridx[r];
        const float4* cw = (const float4*)(cb + (size_t)bi * D_ + half * 32);
        const float4* zr4 = (const float4*)(zg + (size_t)r * D_ + half * 32);
        float2* zqo = (float2*)(out + OUT_ZQ + (size_t)(row0 + r) * D_ + half * 32);
        float csum = 0.f;
#pragma unroll
        for (int j4 = 0; j4 < 8; ++j4) {
            float4 w = cw[j4]; float4 zz = zr4[j4];
            float d0 = w.x - zz.x, d1 = w.y - zz.y, d2 = w.z - zz.z, d3 = w.w - zz.w;
            csum += d0 * d0 + d1 * d1 + d2 * d2 + d3 * d3;
            float2 p0; p0.x = w.x; p0.y = w.y; zqo[j4 * 2] = p0;
            float2 p1; p1.x = w.z; p1.y = w.w; zqo[j4 * 2 + 1] = p1;
        }
        red[tid] = csum;
    }
    __syncthreads();
    for (int o2 = 128; o2 > 0; o2 >>= 1) {
        if (tid < o2) red[tid] += red[tid + o2];
        __syncthreads();
    }
    if (tid == 0) ws[WS_CPART + blockIdx.x] = red[0];
}

// ---------------- decoder: LDS-tiled GEMM + LN + denorm + rec-loss ----------------
#define DR_ 64

__global__ __launch_bounds__(TPB) void k_dec(
    float* __restrict__ ws, const float* __restrict__ x, const float* __restrict__ cb,
    const float* __restrict__ dW1, const float* __restrict__ db1,
    const float* __restrict__ dW2, const float* __restrict__ db2,
    const float* __restrict__ dWr, const float* __restrict__ dbr,
    const float* __restrict__ lng, const float* __restrict__ lnb,
    const float* __restrict__ rw, const float* __restrict__ rb,
    float* __restrict__ out) {
    __shared__ float zqT[64][FHS];
    __shared__ float Hc[64][FHS];
    __shared__ int   ridx[DR_];
    __shared__ float red[TPB];
    const int tid = threadIdx.x;
    const int row0 = blockIdx.x * DR_;
    if (tid < DR_) ridx[tid] = (int)out[OUT_IDX + row0 + tid];
    __syncthreads();
    {
        const float4* cb4 = (const float4*)cb;
#pragma unroll
        for (int it = 0; it < 4; ++it) {
            int e = tid + it * 256;
            int r = e >> 4, j4 = e & 15;
            float4 v = cb4[(size_t)ridx[r] * 16 + j4];
            zqT[j4 * 4 + 0][r] = v.x; zqT[j4 * 4 + 1][r] = v.y;
            zqT[j4 * 4 + 2][r] = v.z; zqT[j4 * 4 + 3][r] = v.w;
        }
    }
    const int ty = tid >> 4, tx = tid & 15;
    const float4* dW14 = (const float4*)dW1;
    float out4[4];
    {
        float b0 = db2[tx] + dbr[tx];
#pragma unroll
        for (int r = 0; r < 4; r++) out4[r] = b0;
    }
    __syncthreads();

    for (int tc = 0; tc < 4; ++tc) {
        float acc[4][4];
        {
            float4 bb1 = ((const float4*)db1)[tc * 16 + tx];
#pragma unroll
            for (int r = 0; r < 4; r++) { acc[r][0] = bb1.x; acc[r][1] = bb1.y; acc[r][2] = bb1.z; acc[r][3] = bb1.w; }
        }
#pragma unroll 4
        for (int j = 0; j < 64; ++j) {
            float4 a = *(const float4*)&zqT[j][ty * 4];
            float4 w = dW14[j * 64 + tc * 16 + tx];
            float ar[4] = {a.x, a.y, a.z, a.w}, wr[4] = {w.x, w.y, w.z, w.w};
#pragma unroll
            for (int r = 0; r < 4; r++)
#pragma unroll
                for (int c = 0; c < 4; c++) acc[r][c] += ar[r] * wr[c];
        }
        __syncthreads();
#pragma unroll
        for (int r = 0; r < 4; r++)
#pragma unroll
            for (int c = 0; c < 4; c++) Hc[tx * 4 + c][ty * 4 + r] = fmaxf(acc[r][c], 0.f);
        __syncthreads();
#pragma unroll 8
        for (int h = 0; h < 64; ++h) {
            float4 a = *(const float4*)&Hc[h][ty * 4];
            float w = dW2[(tc * 64 + h) * 16 + tx];
            out4[0] += a.x * w; out4[1] += a.y * w; out4[2] += a.z * w; out4[3] += a.w * w;
        }
    }
#pragma unroll 8
    for (int j = 0; j < 64; ++j) {
        float4 a = *(const float4*)&zqT[j][ty * 4];
        float w = dWr[j * 16 + tx];
        out4[0] += a.x * w; out4[1] += a.y * w; out4[2] += a.z * w; out4[3] += a.w * w;
    }
    const int n = row0 >> 7;
    const int b = n >> 5, c = n & 31;
    const float sd = ws[WS_STD + n], mn = ws[WS_MEAN + n];
    const float inv = 1.f / (rw[c] + EPS_ * EPS_);
    const float rbc = rb[c];
    const float lg = lng[tx], lb = lnb[tx];
    float part = 0.f;
#pragma unroll
    for (int r = 0; r < 4; r++) {
        float v = out4[r];
        float s = v;
        s += __shfl_xor(s, 1); s += __shfl_xor(s, 2); s += __shfl_xor(s, 4); s += __shfl_xor(s, 8);
        float mean_ = s * (1.f / 16.f);
        float d_ = v - mean_;
        float vv = d_ * d_;
        vv += __shfl_xor(vv, 1); vv += __shfl_xor(vv, 2); vv += __shfl_xor(vv, 4); vv += __shfl_xor(vv, 8);
        float rstd = 1.f / sqrtf(vv * (1.f / 16.f) + EPS_);
        float yv = d_ * rstd * lg + lb;
        float rr = (yv - rbc) * inv * sd + mn;
        int row = row0 + ty * 4 + r;
        int p = row & 127;
        size_t xi = (size_t)b * L_ * C_ + (size_t)(p * PL_ + tx) * C_ + c;
        out[OUT_R + xi] = rr;
        float dx = x[xi] - rr; part += dx * dx;
    }
    red[tid] = part;
    __syncthreads();
    for (int o2 = 128; o2 > 0; o2 >>= 1) {
        if (tid < o2) red[tid] += red[tid + o2];
        __syncthreads();
    }
    if (tid == 0) ws[WS_RPART + blockIdx.x] = red[0];
}

// ---------------- final scalar reductions ----------------
__global__ void k_final(float* __restrict__ ws, float* __restrict__ out) {
    __shared__ float sh[TPB];
    int tid = threadIdx.x;
    float cs = 0.f;
    for (int i2 = tid; i2 < 1024; i2 += TPB) cs += ws[WS_CPART + i2];
    sh[tid] = cs; __syncthreads();
    for (int o2 = 128; o2 > 0; o2 >>= 1) { if (tid < o2) sh[tid] += sh[tid + o2]; __syncthreads(); }
    float csum = sh[0]; __syncthreads();
    float rs = 0.f;
    for (int i2 = tid; i2 < 2048; i2 += TPB) rs += ws[WS_RPART + i2];
    sh[tid] = rs; __syncthreads();
    for (int o2 = 128; o2 > 0; o2 >>= 1) { if (tid < o2) sh[tid] += sh[tid + o2]; __syncthreads(); }
    float rsum = sh[0]; __syncthreads();
    const unsigned int* counts = (const unsigned int*)ws + WS_COUNTS;
    float H = 0.f;
    for (int k2 = tid; k2 < K_; k2 += TPB) {
        float p = (float)counts[k2] / (131072.f + EPS_);
        H += p * logf(p + EPS_);
    }
    sh[tid] = H; __syncthreads();
    for (int o2 = 128; o2 > 0; o2 >>= 1) { if (tid < o2) sh[tid] += sh[tid + o2]; __syncthreads(); }
    if (tid == 0) {
        float rec = rsum / 2097152.f;
        float msd = csum / 8388608.f;
        float cl = (1.f + BETA_) * msd;
        out[OUT_LOSS] = rec + CW_ * cl;
        out[OUT_REC] = rec;
        out[OUT_PERP] = expf(-sh[0]);
    }
}

extern "C" void kernel_launch(void* const* d_in, const int* in_sizes, int n_in,
                              void* d_out, int out_size, void* d_ws, size_t ws_size,
                              hipStream_t stream) {
    const float* x    = (const float*)d_in[0];
    const float* rw   = (const float*)d_in[1];
    const float* rb   = (const float*)d_in[2];
    const float* inpW = (const float*)d_in[3];
    const float* inpb = (const float*)d_in[4];
    const float* Wq   = (const float*)d_in[5];
    const float* bq   = (const float*)d_in[6];
    const float* Wk   = (const float*)d_in[7];
    const float* bk   = (const float*)d_in[8];
    const float* Wv   = (const float*)d_in[9];
    const float* bv   = (const float*)d_in[10];
    const float* Wo   = (const float*)d_in[11];
    const float* bo   = (const float*)d_in[12];
    const float* g1   = (const float*)d_in[13];
    const float* b1   = (const float*)d_in[14];
    const float* fW1  = (const float*)d_in[15];
    const float* fb1  = (const float*)d_in[16];
    const float* fW2  = (const float*)d_in[17];
    const float* fb2  = (const float*)d_in[18];
    const float* g2   = (const float*)d_in[19];
    const float* b2   = (const float*)d_in[20];
    const float* cb   = (const float*)d_in[21];
    const float* dW1  = (const float*)d_in[22];
    const float* db1  = (const float*)d_in[23];
    const float* dW2  = (const float*)d_in[24];
    const float* db2  = (const float*)d_in[25];
    const float* dWr  = (const float*)d_in[26];
    const float* dbr  = (const float*)d_in[27];
    const float* lng  = (const float*)d_in[28];
    const float* lnb  = (const float*)d_in[29];
    float* ws  = (float*)d_ws;
    float* out = (float*)d_out;

    hipMemsetAsync((char*)d_ws + (size_t)WS_COUNTS * 4, 0, 512 * 4, stream);
    k_prep<<<48, TPB, 0, stream>>>(Wq, Wk, Wv, cb, ws);
    k_stats<<<N_, TPB, 0, stream>>>(x, ws);
    k_embed<<<(M_ * D_) / TPB, TPB, 0, stream>>>(x, rw, rb, inpW, inpb, ws);
    k_attn<<<N_ * 4, TPB, 0, stream>>>(ws, bq, bk, bv);
    k_woffn<<<M_ / 64, TPB, 0, stream>>>(ws, Wo, bo, g1, b1, fW1, fb1, fW2, fb2, g2, b2);
    k_quant<<<M_ / QROWS, TPB, 0, stream>>>(ws, cb, out);
    k_dec<<<M_ / DR_, TPB, 0, stream>>>(ws, x, cb, dW1, db1, dW2, db2, dWr, dbr, lng, lnb, rw, rb, out);
    k_final<<<1, TPB, 0, stream>>>(ws, out);
}

// Round 10
// 712.321 us; speedup vs baseline: 1.1249x; 1.1249x over previous
//
#include <hip/hip_runtime.h>
#include <math.h>

#define TPB 256

// problem dims
#define B_  32
#define L_  2048
#define C_  32
#define PL_ 16
#define P_  128
#define D_  64
#define HE_ 256
#define HD_ 256
#define K_  512
#define N_  1024      // B*C
#define M_  131072    // N_*P_

#define EPS_  1e-5f
#define BETA_ 0.25f
#define CW_   0.2f

// output offsets (floats). order: loss_total, rec_loss, z_q_st, r, indices, perplexity
#define OUT_LOSS 0
#define OUT_REC  1
#define OUT_ZQ   2
#define OUT_R    8388610      // 2 + M_*D_
#define OUT_IDX  10485762     // OUT_R + B_*L_*C_
#define OUT_PERP 10616834     // OUT_IDX + M_

// workspace offsets (floats)
#define WS_MEAN   0
#define WS_STD    1024
#define WS_QT     2048        // WqT [64 t][64 j]
#define WS_KT     6144        // WkT
#define WS_VT     10240       // WvT
#define WS_E2     34816
#define WS_COUNTS 35328
#define WS_CPART  35840       // 1024 entries, ends at 36864
#define WS_H0     36864
#define WS_H1     8425472     // WS_H0 + M_*D_  (AO; dead after k_woffn -> RPART scratch)
#define WS_RPART  WS_H1

// ---------------- prep: transposes (Wq, Wk, Wv) + codebook e2 ----------------
__global__ void k_prep(const float* __restrict__ Wq, const float* __restrict__ Wk,
                       const float* __restrict__ Wv,
                       const float* __restrict__ cb, float* __restrict__ ws) {
    int g = blockIdx.x * TPB + threadIdx.x;
    if (g < 4096) { int t = g >> 6, j = g & 63; ws[WS_QT + g] = Wq[j * D_ + t]; }
    else if (g < 8192) { int g2 = g - 4096; int t = g2 >> 6, j = g2 & 63; ws[WS_KT + g2] = Wk[j * D_ + t]; }
    else if (g < 12288) { int g2 = g - 8192; int t = g2 >> 6, j = g2 & 63; ws[WS_VT + g2] = Wv[j * D_ + t]; }
    if (g < K_) {
        float s = 0.f;
        for (int j = 0; j < D_; j++) { float v = cb[g * D_ + j]; s += v * v; }
        ws[WS_E2 + g] = s;
    }
}

// ---------------- RevIN stats over time dim ----------------
__global__ void k_stats(const float* __restrict__ x, float* __restrict__ ws) {
    int bc = blockIdx.x;
    int b = bc >> 5, c = bc & 31;
    const float* xp = x + (size_t)b * L_ * C_ + c;
    float s = 0.f, s2 = 0.f;
    for (int l = threadIdx.x; l < L_; l += TPB) { float v = xp[(size_t)l * C_]; s += v; s2 += v * v; }
    __shared__ float sh[TPB], sh2[TPB];
    sh[threadIdx.x] = s; sh2[threadIdx.x] = s2; __syncthreads();
    for (int o2 = 128; o2 > 0; o2 >>= 1) {
        if (threadIdx.x < o2) { sh[threadIdx.x] += sh[threadIdx.x + o2]; sh2[threadIdx.x] += sh2[threadIdx.x + o2]; }
        __syncthreads();
    }
    if (threadIdx.x == 0) {
        float m = sh[0] / (float)L_;
        float var = sh2[0] / (float)L_ - m * m;
        ws[WS_MEAN + bc] = m;
        ws[WS_STD + bc] = sqrtf(var + EPS_);
    }
}

// ---------------- patchify + input embedding ----------------
__global__ __launch_bounds__(TPB) void k_embed(
    const float* __restrict__ x, const float* __restrict__ rw, const float* __restrict__ rb,
    const float* __restrict__ inpW, const float* __restrict__ inpb, float* __restrict__ ws) {
    int idx = blockIdx.x * TPB + threadIdx.x;          // < M_*D_
    int row = idx >> 6, d = idx & 63;
    int n = row >> 7, p = row & 127;
    int b = n >> 5, c = n & 31;
    float m = ws[WS_MEAN + n], sd = ws[WS_STD + n];
    float w = rw[c], bb = rb[c];
    const float* xp = x + (size_t)b * L_ * C_ + (size_t)p * PL_ * C_ + c;
    float acc = inpb[d];
#pragma unroll
    for (int j = 0; j < PL_; j++) {
        float xv = xp[(size_t)j * C_];
        float xn = (xv - m) / sd * w + bb;
        acc += xn * inpW[j * D_ + d];
    }
    ws[WS_H0 + (size_t)idx] = acc;
}

// ---------------- attention v10: v8 staging + fused K/V + max-free flash ----------------
#define HSS  68         // hs row stride
#define HS_  0          // 128*68 = 8704
#define KH_  8704       // 128*16 = 2048
#define VH_  10752      // 2048
#define SMF  12800      // 51200 bytes

__global__ __launch_bounds__(TPB) void k_attn(
    float* __restrict__ ws,
    const float* __restrict__ bq, const float* __restrict__ bk, const float* __restrict__ bv) {
    __shared__ float sm[SMF];
    const int tid = threadIdx.x;
    const int n = blockIdx.x >> 2, hh = blockIdx.x & 3;
    const float* h0 = ws + WS_H0 + (size_t)n * (P_ * D_);
    float* agl = ws + WS_H1 + (size_t)n * (P_ * D_);   // AO output

    // stage hs
    {
        const float4* h04 = (const float4*)h0;
#pragma unroll
        for (int it = 0; it < 8; ++it) {
            int e = tid + it * 256;
            int r = e >> 4, j4 = e & 15;
            *(float4*)(sm + HS_ + r * HSS + j4 * 4) = h04[e];
        }
    }
    __syncthreads();

    const int t_ = tid & 15, ib = tid >> 4;
    const float4* WqT4 = (const float4*)(ws + WS_QT);
    const float4* WkT4 = (const float4*)(ws + WS_KT);
    const float4* WvT4 = (const float4*)(ws + WS_VT);

    // ---- fused K+V: thread owns dim t_, rows ib+16*it; each h4 read once ----
    {
        float4 wk[16], wv[16];
        const float4* kr = WkT4 + (size_t)(hh * 16 + t_) * 16;
        const float4* vr = WvT4 + (size_t)(hh * 16 + t_) * 16;
#pragma unroll
        for (int j4 = 0; j4 < 16; j4++) { wk[j4] = kr[j4]; wv[j4] = vr[j4]; }
        float bbk = bk[hh * 16 + t_], bbv = bv[hh * 16 + t_];
#pragma unroll
        for (int it = 0; it < 8; it++) {
            int i2 = ib + it * 16;
            const float4* hr = (const float4*)(sm + HS_ + i2 * HSS);
            float accK = bbk, accV = bbv;
#pragma unroll
            for (int j4 = 0; j4 < 16; j4++) {
                float4 h4 = hr[j4];
                float4 k4 = wk[j4], v4 = wv[j4];
                accK += h4.x * k4.x + h4.y * k4.y + h4.z * k4.z + h4.w * k4.w;
                accV += h4.x * v4.x + h4.y * v4.y + h4.z * v4.z + h4.w * v4.w;
            }
            sm[KH_ + i2 * 16 + t_] = accK;
            sm[VH_ + i2 * 16 + t_] = accV;
        }
    }
    // ---- q: pair (row i, half) computes 8 dims from LDS hs, exchange -> full q ----
    const int i = tid >> 1, half = tid & 1;
    float q0[8], q1[8];
    {
        float4 hreg[16];
        const float4* hr = (const float4*)(sm + HS_ + i * HSS);
#pragma unroll
        for (int j4 = 0; j4 < 16; j4++) hreg[j4] = hr[j4];
        float qh[8];
#pragma unroll
        for (int u = 0; u < 8; u++) {
            const float4* wr = WqT4 + (size_t)(hh * 16 + half * 8 + u) * 16;
            float acc = bq[hh * 16 + half * 8 + u];
#pragma unroll
            for (int j4 = 0; j4 < 16; j4++) {
                float4 w4 = wr[j4];
                acc += hreg[j4].x * w4.x + hreg[j4].y * w4.y + hreg[j4].z * w4.z + hreg[j4].w * w4.w;
            }
            qh[u] = acc;
        }
#pragma unroll
        for (int u = 0; u < 8; u++) {
            float oth = __shfl_xor(qh[u], 1);
            q0[u] = half ? oth : qh[u];
            q1[u] = half ? qh[u] : oth;
        }
    }
    __syncthreads();   // kh/vh ready
    // ---- max-free single-pass softmax over parity keys (scores |s|<<1) ----
    float S = 0.f;
    float o[16];
#pragma unroll
    for (int u = 0; u < 16; u++) o[u] = 0.f;
    const float4* kh4 = (const float4*)(sm + KH_);
    const float4* vh4 = (const float4*)(sm + VH_);
#pragma unroll 4
    for (int m2 = 0; m2 < 64; m2++) {
        int m = m2 * 2 + half;
        float4 a0 = kh4[m * 4 + 0], a1 = kh4[m * 4 + 1], a2 = kh4[m * 4 + 2], a3 = kh4[m * 4 + 3];
        float sp = q0[0] * a0.x + q0[1] * a0.y + q0[2] * a0.z + q0[3] * a0.w
                 + q0[4] * a1.x + q0[5] * a1.y + q0[6] * a1.z + q0[7] * a1.w
                 + q1[0] * a2.x + q1[1] * a2.y + q1[2] * a2.z + q1[3] * a2.w
                 + q1[4] * a3.x + q1[5] * a3.y + q1[6] * a3.z + q1[7] * a3.w;
        float p = __expf(sp * 0.25f);   // exact softmax: max-shift unnecessary at this scale
        S += p;
        float4 v0 = vh4[m * 4 + 0], v1 = vh4[m * 4 + 1], v2 = vh4[m * 4 + 2], v3 = vh4[m * 4 + 3];
        o[0] += p * v0.x; o[1] += p * v0.y; o[2] += p * v0.z; o[3] += p * v0.w;
        o[4] += p * v1.x; o[5] += p * v1.y; o[6] += p * v1.z; o[7] += p * v1.w;
        o[8] += p * v2.x; o[9] += p * v2.y; o[10] += p * v2.z; o[11] += p * v2.w;
        o[12] += p * v3.x; o[13] += p * v3.y; o[14] += p * v3.z; o[15] += p * v3.w;
    }
    // ---- merge pair (pure add) ----
    {
        S += __shfl_xor(S, 1);
        float inv = 1.f / S;
        float wv[8];
#pragma unroll
        for (int u = 0; u < 8; u++) {
            float lo = o[u] + __shfl_xor(o[u], 1);
            float hi = o[8 + u] + __shfl_xor(o[8 + u], 1);
            wv[u] = (half ? hi : lo) * inv;
        }
        float4 r0, r1;
        r0.x = wv[0]; r0.y = wv[1]; r0.z = wv[2]; r0.w = wv[3];
        r1.x = wv[4]; r1.y = wv[5]; r1.z = wv[6]; r1.w = wv[7];
        float4* ap4 = (float4*)(agl + (size_t)i * D_ + hh * 16 + half * 8);
        ap4[0] = r0; ap4[1] = r1;
    }
}

// ---------------- fused Wo+LN1+FFN+LN2: AO -> z, no h1 round-trip ----------------
#define FHS  68

__global__ __launch_bounds__(TPB) void k_woffn(
    float* __restrict__ ws, const float* __restrict__ Wo, const float* __restrict__ bo,
    const float* __restrict__ g1, const float* __restrict__ b1,
    const float* __restrict__ fW1, const float* __restrict__ fb1,
    const float* __restrict__ fW2, const float* __restrict__ fb2,
    const float* __restrict__ g2, const float* __restrict__ b2) {
    __shared__ float bufA[64][FHS];   // aoT in phase A, Hc in phase B
    __shared__ float hT[64][FHS];     // h1 transposed [d][row]
    const int tid = threadIdx.x;
    const int row0 = blockIdx.x * 64;
    const float* aog = ws + WS_H1 + (size_t)row0 * D_;

    // stage aoT
    {
        const float4* ao4 = (const float4*)aog;
#pragma unroll
        for (int it = 0; it < 4; ++it) {
            int e = tid + it * 256;
            int r = e >> 4, j4 = e & 15;
            float4 v = ao4[e];
            bufA[j4 * 4 + 0][r] = v.x; bufA[j4 * 4 + 1][r] = v.y;
            bufA[j4 * 4 + 2][r] = v.z; bufA[j4 * 4 + 3][r] = v.w;
        }
    }
    const int ty = tid >> 4, tx = tid & 15;
    // ---- phase A: Wo GEMM ----
    float acc[4][4];
    {
        float4 bb = ((const float4*)bo)[tx];
#pragma unroll
        for (int r = 0; r < 4; r++) { acc[r][0] = bb.x; acc[r][1] = bb.y; acc[r][2] = bb.z; acc[r][3] = bb.w; }
    }
    __syncthreads();
    const float4* Wo4 = (const float4*)Wo;
#pragma unroll 4
    for (int j = 0; j < 64; ++j) {
        float4 a = *(const float4*)&bufA[j][ty * 4];
        float4 w = Wo4[j * 16 + tx];
        float ar[4] = {a.x, a.y, a.z, a.w}, wr[4] = {w.x, w.y, w.z, w.w};
#pragma unroll
        for (int r = 0; r < 4; r++)
#pragma unroll
            for (int c = 0; c < 4; c++) acc[r][c] += ar[r] * wr[c];
    }
    // residual + LN1 -> h1v (kept in regs)
    float h1v[4][4];
    {
        const float4* h04 = (const float4*)(ws + WS_H0 + (size_t)row0 * D_);
        float4 gg = ((const float4*)g1)[tx], bbn = ((const float4*)b1)[tx];
#pragma unroll
        for (int r = 0; r < 4; r++) {
            float4 res = h04[(ty * 4 + r) * 16 + tx];
            acc[r][0] += res.x; acc[r][1] += res.y; acc[r][2] += res.z; acc[r][3] += res.w;
            float s = acc[r][0] + acc[r][1] + acc[r][2] + acc[r][3];
            s += __shfl_xor(s, 1); s += __shfl_xor(s, 2); s += __shfl_xor(s, 4); s += __shfl_xor(s, 8);
            float mean_ = s * (1.f / 64.f);
            float vv = 0.f;
#pragma unroll
            for (int c = 0; c < 4; c++) { float d_ = acc[r][c] - mean_; vv += d_ * d_; }
            vv += __shfl_xor(vv, 1); vv += __shfl_xor(vv, 2); vv += __shfl_xor(vv, 4); vv += __shfl_xor(vv, 8);
            float rstd = 1.f / sqrtf(vv * (1.f / 64.f) + EPS_);
            h1v[r][0] = (acc[r][0] - mean_) * rstd * gg.x + bbn.x;
            h1v[r][1] = (acc[r][1] - mean_) * rstd * gg.y + bbn.y;
            h1v[r][2] = (acc[r][2] - mean_) * rstd * gg.z + bbn.z;
            h1v[r][3] = (acc[r][3] - mean_) * rstd * gg.w + bbn.w;
        }
    }
    // scatter h1 into hT[d][row]
#pragma unroll
    for (int r = 0; r < 4; r++)
#pragma unroll
        for (int c = 0; c < 4; c++) hT[tx * 4 + c][ty * 4 + r] = h1v[r][c];
    // ---- phase B: FFN GEMMs (Hc aliases bufA) ----
    const float4* W14 = (const float4*)fW1;
    const float4* W24 = (const float4*)fW2;
    float outv[4][4];
    {
        float4 bb = ((const float4*)fb2)[tx];
#pragma unroll
        for (int r = 0; r < 4; r++) { outv[r][0] = bb.x; outv[r][1] = bb.y; outv[r][2] = bb.z; outv[r][3] = bb.w; }
    }
    __syncthreads();   // hT ready; all aoT reads done -> bufA reusable

    for (int tc = 0; tc < 4; ++tc) {
        float a2[4][4];
        {
            float4 bb1 = ((const float4*)fb1)[tc * 16 + tx];
#pragma unroll
            for (int r = 0; r < 4; r++) { a2[r][0] = bb1.x; a2[r][1] = bb1.y; a2[r][2] = bb1.z; a2[r][3] = bb1.w; }
        }
#pragma unroll 4
        for (int j = 0; j < 64; ++j) {
            float4 a = *(const float4*)&hT[j][ty * 4];
            float4 w = W14[j * 64 + tc * 16 + tx];
            float ar[4] = {a.x, a.y, a.z, a.w}, wr[4] = {w.x, w.y, w.z, w.w};
#pragma unroll
            for (int r = 0; r < 4; r++)
#pragma unroll
                for (int c = 0; c < 4; c++) a2[r][c] += ar[r] * wr[c];
        }
        __syncthreads();   // prev Hc reads done
#pragma unroll
        for (int r = 0; r < 4; r++)
#pragma unroll
            for (int c = 0; c < 4; c++) bufA[tx * 4 + c][ty * 4 + r] = fmaxf(a2[r][c], 0.f);
        __syncthreads();
#pragma unroll 4
        for (int h = 0; h < 64; ++h) {
            float4 a = *(const float4*)&bufA[h][ty * 4];
            float4 w = W24[(tc * 64 + h) * 16 + tx];
            float ar[4] = {a.x, a.y, a.z, a.w}, wr[4] = {w.x, w.y, w.z, w.w};
#pragma unroll
            for (int r = 0; r < 4; r++)
#pragma unroll
                for (int c = 0; c < 4; c++) outv[r][c] += ar[r] * wr[c];
        }
    }
    // residual (h1v) + LN2 -> z
    {
        float4 gg = ((const float4*)g2)[tx], bb = ((const float4*)b2)[tx];
        float4* zp = (float4*)(ws + WS_H0 + (size_t)row0 * D_);
#pragma unroll
        for (int r = 0; r < 4; r++) {
            outv[r][0] += h1v[r][0]; outv[r][1] += h1v[r][1];
            outv[r][2] += h1v[r][2]; outv[r][3] += h1v[r][3];
            float s = outv[r][0] + outv[r][1] + outv[r][2] + outv[r][3];
            s += __shfl_xor(s, 1); s += __shfl_xor(s, 2); s += __shfl_xor(s, 4); s += __shfl_xor(s, 8);
            float mean_ = s * (1.f / 64.f);
            float vv = 0.f;
#pragma unroll
            for (int c = 0; c < 4; c++) { float d_ = outv[r][c] - mean_; vv += d_ * d_; }
            vv += __shfl_xor(vv, 1); vv += __shfl_xor(vv, 2); vv += __shfl_xor(vv, 4); vv += __shfl_xor(vv, 8);
            float rstd = 1.f / sqrtf(vv * (1.f / 64.f) + EPS_);
            float4 z;
            z.x = (outv[r][0] - mean_) * rstd * gg.x + bb.x;
            z.y = (outv[r][1] - mean_) * rstd * gg.y + bb.y;
            z.z = (outv[r][2] - mean_) * rstd * gg.z + bb.z;
            z.w = (outv[r][3] - mean_) * rstd * gg.w + bb.w;
            zp[(ty * 4 + r) * 16 + tx] = z;
        }
    }
}

// ---------------- quantizer: LDS-tiled register-blocked distance GEMM ----------------
#define QROWS 128
#define QKT   64
#define ZTS   132
#define CBS   68

__global__ __launch_bounds__(TPB) void k_quant(
    float* __restrict__ ws, const float* __restrict__ cb, float* __restrict__ out) {
    __shared__ float zT[64][ZTS];
    __shared__ float cbT[64][CBS];
    __shared__ float z2s[QROWS];
    __shared__ float e2t[QKT];
    __shared__ int   ridx[QROWS];
    __shared__ float red[TPB];

    const int tid = threadIdx.x;
    const int row0 = blockIdx.x * QROWS;
    const float* zg = ws + WS_H0 + (size_t)row0 * D_;
    const float4* zg4 = (const float4*)zg;
    const float4* cbg4 = (const float4*)cb;

    {
        int j4 = tid >> 4;
#pragma unroll
        for (int it = 0; it < 8; ++it) {
            int r = (tid & 15) + it * 16;
            float4 v = zg4[r * 16 + j4];
            zT[j4 * 4 + 0][r] = v.x; zT[j4 * 4 + 1][r] = v.y;
            zT[j4 * 4 + 2][r] = v.z; zT[j4 * 4 + 3][r] = v.w;
        }
    }
    if (tid < QROWS) {
        const float4* zr = (const float4*)(zg + (size_t)tid * D_);
        float s = 0.f;
#pragma unroll
        for (int j = 0; j < 16; j++) { float4 v = zr[j]; s += v.x * v.x + v.y * v.y + v.z * v.z + v.w * v.w; }
        z2s[tid] = s;
    }

    const int ty = tid >> 4, tx = tid & 15;
    float best[8]; int bidx[8];
#pragma unroll
    for (int u = 0; u < 8; u++) { best[u] = 3.4e38f; bidx[u] = 0; }

    for (int t = 0; t < K_ / QKT; ++t) {
        const int k0 = t * QKT;
        __syncthreads();
        {
            int j4 = tid >> 4;
#pragma unroll
            for (int it = 0; it < 4; ++it) {
                int kk = (tid & 15) + it * 16;
                float4 v = cbg4[(size_t)(k0 + kk) * 16 + j4];
                cbT[j4 * 4 + 0][kk] = v.x; cbT[j4 * 4 + 1][kk] = v.y;
                cbT[j4 * 4 + 2][kk] = v.z; cbT[j4 * 4 + 3][kk] = v.w;
            }
        }
        if (tid < QKT) e2t[tid] = ws[WS_E2 + k0 + tid];
        __syncthreads();

        float acc[8][4];
#pragma unroll
        for (int u = 0; u < 8; u++)
#pragma unroll
            for (int c = 0; c < 4; c++) acc[u][c] = 0.f;

        for (int j = 0; j < 64; ++j) {
            float4 a0 = *(const float4*)&zT[j][ty * 8];
            float4 a1 = *(const float4*)&zT[j][ty * 8 + 4];
            float4 b0 = *(const float4*)&cbT[j][tx * 4];
            float ar[8] = {a0.x, a0.y, a0.z, a0.w, a1.x, a1.y, a1.z, a1.w};
            float br[4] = {b0.x, b0.y, b0.z, b0.w};
#pragma unroll
            for (int u = 0; u < 8; u++)
#pragma unroll
                for (int c = 0; c < 4; c++) acc[u][c] += ar[u] * br[c];
        }

#pragma unroll
        for (int u = 0; u < 8; u++) {
            float z2v = z2s[ty * 8 + u];
#pragma unroll
            for (int c = 0; c < 4; c++) {
                float dist = (z2v + e2t[tx * 4 + c]) - 2.f * acc[u][c];
                int kidx = k0 + tx * 4 + c;
                if (dist < best[u]) { best[u] = dist; bidx[u] = kidx; }
            }
        }
    }

#pragma unroll
    for (int m = 1; m <= 8; m <<= 1) {
#pragma unroll
        for (int u = 0; u < 8; u++) {
            float ob = __shfl_xor(best[u], m, 64);
            int oi = __shfl_xor(bidx[u], m, 64);
            if (ob < best[u] || (ob == best[u] && oi < bidx[u])) { best[u] = ob; bidx[u] = oi; }
        }
    }
    if (tx == 0) {
#pragma unroll
        for (int u = 0; u < 8; u++) ridx[ty * 8 + u] = bidx[u];
    }
    __syncthreads();

    if (tid < QROWS) {
        int bi = ridx[tid];
        out[OUT_IDX + row0 + tid] = (float)bi;
        atomicAdd((unsigned int*)ws + WS_COUNTS + bi, 1u);
    }
    {
        int r = tid >> 1, half = tid & 1;
        int bi = ridx[r];
        const float4* cw = (const float4*)(cb + (size_t)bi * D_ + half * 32);
        const float4* zr4 = (const float4*)(zg + (size_t)r * D_ + half * 32);
        float2* zqo = (float2*)(out + OUT_ZQ + (size_t)(row0 + r) * D_ + half * 32);
        float csum = 0.f;
#pragma unroll
        for (int j4 = 0; j4 < 8; ++j4) {
            float4 w = cw[j4]; float4 zz = zr4[j4];
            float d0 = w.x - zz.x, d1 = w.y - zz.y, d2 = w.z - zz.z, d3 = w.w - zz.w;
            csum += d0 * d0 + d1 * d1 + d2 * d2 + d3 * d3;
            float2 p0; p0.x = w.x; p0.y = w.y; zqo[j4 * 2] = p0;
            float2 p1; p1.x = w.z; p1.y = w.w; zqo[j4 * 2 + 1] = p1;
        }
        red[tid] = csum;
    }
    __syncthreads();
    for (int o2 = 128; o2 > 0; o2 >>= 1) {
        if (tid < o2) red[tid] += red[tid + o2];
        __syncthreads();
    }
    if (tid == 0) ws[WS_CPART + blockIdx.x] = red[0];
}

// ---------------- decoder: LDS-tiled GEMM + LN + denorm + rec-loss ----------------
#define DR_ 64

__global__ __launch_bounds__(TPB) void k_dec(
    float* __restrict__ ws, const float* __restrict__ x, const float* __restrict__ cb,
    const float* __restrict__ dW1, const float* __restrict__ db1,
    const float* __restrict__ dW2, const float* __restrict__ db2,
    const float* __restrict__ dWr, const float* __restrict__ dbr,
    const float* __restrict__ lng, const float* __restrict__ lnb,
    const float* __restrict__ rw, const float* __restrict__ rb,
    float* __restrict__ out) {
    __shared__ float zqT[64][FHS];
    __shared__ float Hc[64][FHS];
    __shared__ int   ridx[DR_];
    __shared__ float red[TPB];
    const int tid = threadIdx.x;
    const int row0 = blockIdx.x * DR_;
    if (tid < DR_) ridx[tid] = (int)out[OUT_IDX + row0 + tid];
    __syncthreads();
    {
        const float4* cb4 = (const float4*)cb;
#pragma unroll
        for (int it = 0; it < 4; ++it) {
            int e = tid + it * 256;
            int r = e >> 4, j4 = e & 15;
            float4 v = cb4[(size_t)ridx[r] * 16 + j4];
            zqT[j4 * 4 + 0][r] = v.x; zqT[j4 * 4 + 1][r] = v.y;
            zqT[j4 * 4 + 2][r] = v.z; zqT[j4 * 4 + 3][r] = v.w;
        }
    }
    const int ty = tid >> 4, tx = tid & 15;
    const float4* dW14 = (const float4*)dW1;
    float out4[4];
    {
        float b0 = db2[tx] + dbr[tx];
#pragma unroll
        for (int r = 0; r < 4; r++) out4[r] = b0;
    }
    __syncthreads();

    for (int tc = 0; tc < 4; ++tc) {
        float acc[4][4];
        {
            float4 bb1 = ((const float4*)db1)[tc * 16 + tx];
#pragma unroll
            for (int r = 0; r < 4; r++) { acc[r][0] = bb1.x; acc[r][1] = bb1.y; acc[r][2] = bb1.z; acc[r][3] = bb1.w; }
        }
#pragma unroll 4
        for (int j = 0; j < 64; ++j) {
            float4 a = *(const float4*)&zqT[j][ty * 4];
            float4 w = dW14[j * 64 + tc * 16 + tx];
            float ar[4] = {a.x, a.y, a.z, a.w}, wr[4] = {w.x, w.y, w.z, w.w};
#pragma unroll
            for (int r = 0; r < 4; r++)
#pragma unroll
                for (int c = 0; c < 4; c++) acc[r][c] += ar[r] * wr[c];
        }
        __syncthreads();
#pragma unroll
        for (int r = 0; r < 4; r++)
#pragma unroll
            for (int c = 0; c < 4; c++) Hc[tx * 4 + c][ty * 4 + r] = fmaxf(acc[r][c], 0.f);
        __syncthreads();
#pragma unroll 8
        for (int h = 0; h < 64; ++h) {
            float4 a = *(const float4*)&Hc[h][ty * 4];
            float w = dW2[(tc * 64 + h) * 16 + tx];
            out4[0] += a.x * w; out4[1] += a.y * w; out4[2] += a.z * w; out4[3] += a.w * w;
        }
    }
#pragma unroll 8
    for (int j = 0; j < 64; ++j) {
        float4 a = *(const float4*)&zqT[j][ty * 4];
        float w = dWr[j * 16 + tx];
        out4[0] += a.x * w; out4[1] += a.y * w; out4[2] += a.z * w; out4[3] += a.w * w;
    }
    const int n = row0 >> 7;
    const int b = n >> 5, c = n & 31;
    const float sd = ws[WS_STD + n], mn = ws[WS_MEAN + n];
    const float inv = 1.f / (rw[c] + EPS_ * EPS_);
    const float rbc = rb[c];
    const float lg = lng[tx], lb = lnb[tx];
    float part = 0.f;
#pragma unroll
    for (int r = 0; r < 4; r++) {
        float v = out4[r];
        float s = v;
        s += __shfl_xor(s, 1); s += __shfl_xor(s, 2); s += __shfl_xor(s, 4); s += __shfl_xor(s, 8);
        float mean_ = s * (1.f / 16.f);
        float d_ = v - mean_;
        float vv = d_ * d_;
        vv += __shfl_xor(vv, 1); vv += __shfl_xor(vv, 2); vv += __shfl_xor(vv, 4); vv += __shfl_xor(vv, 8);
        float rstd = 1.f / sqrtf(vv * (1.f / 16.f) + EPS_);
        float yv = d_ * rstd * lg + lb;
        float rr = (yv - rbc) * inv * sd + mn;
        int row = row0 + ty * 4 + r;
        int p = row & 127;
        size_t xi = (size_t)b * L_ * C_ + (size_t)(p * PL_ + tx) * C_ + c;
        out[OUT_R + xi] = rr;
        float dx = x[xi] - rr; part += dx * dx;
    }
    red[tid] = part;
    __syncthreads();
    for (int o2 = 128; o2 > 0; o2 >>= 1) {
        if (tid < o2) red[tid] += red[tid + o2];
        __syncthreads();
    }
    if (tid == 0) ws[WS_RPART + blockIdx.x] = red[0];
}

// ---------------- final scalar reductions ----------------
__global__ void k_final(float* __restrict__ ws, float* __restrict__ out) {
    __shared__ float sh[TPB];
    int tid = threadIdx.x;
    float cs = 0.f;
    for (int i2 = tid; i2 < 1024; i2 += TPB) cs += ws[WS_CPART + i2];
    sh[tid] = cs; __syncthreads();
    for (int o2 = 128; o2 > 0; o2 >>= 1) { if (tid < o2) sh[tid] += sh[tid + o2]; __syncthreads(); }
    float csum = sh[0]; __syncthreads();
    float rs = 0.f;
    for (int i2 = tid; i2 < 2048; i2 += TPB) rs += ws[WS_RPART + i2];
    sh[tid] = rs; __syncthreads();
    for (int o2 = 128; o2 > 0; o2 >>= 1) { if (tid < o2) sh[tid] += sh[tid + o2]; __syncthreads(); }
    float rsum = sh[0]; __syncthreads();
    const unsigned int* counts = (const unsigned int*)ws + WS_COUNTS;
    float H = 0.f;
    for (int k2 = tid; k2 < K_; k2 += TPB) {
        float p = (float)counts[k2] / (131072.f + EPS_);
        H += p * logf(p + EPS_);
    }
    sh[tid] = H; __syncthreads();
    for (int o2 = 128; o2 > 0; o2 >>= 1) { if (tid < o2) sh[tid] += sh[tid + o2]; __syncthreads(); }
    if (tid == 0) {
        float rec = rsum / 2097152.f;
        float msd = csum / 8388608.f;
        float cl = (1.f + BETA_) * msd;
        out[OUT_LOSS] = rec + CW_ * cl;
        out[OUT_REC] = rec;
        out[OUT_PERP] = expf(-sh[0]);
    }
}

extern "C" void kernel_launch(void* const* d_in, const int* in_sizes, int n_in,
                              void* d_out, int out_size, void* d_ws, size_t ws_size,
                              hipStream_t stream) {
    const float* x    = (const float*)d_in[0];
    const float* rw   = (const float*)d_in[1];
    const float* rb   = (const float*)d_in[2];
    const float* inpW = (const float*)d_in[3];
    const float* inpb = (const float*)d_in[4];
    const float* Wq   = (const float*)d_in[5];
    const float* bq   = (const float*)d_in[6];
    const float* Wk   = (const float*)d_in[7];
    const float* bk   = (const float*)d_in[8];
    const float* Wv   = (const float*)d_in[9];
    const float* bv   = (const float*)d_in[10];
    const float* Wo   = (const float*)d_in[11];
    const float* bo   = (const float*)d_in[12];
    const float* g1   = (const float*)d_in[13];
    const float* b1   = (const float*)d_in[14];
    const float* fW1  = (const float*)d_in[15];
    const float* fb1  = (const float*)d_in[16];
    const float* fW2  = (const float*)d_in[17];
    const float* fb2  = (const float*)d_in[18];
    const float* g2   = (const float*)d_in[19];
    const float* b2   = (const float*)d_in[20];
    const float* cb   = (const float*)d_in[21];
    const float* dW1  = (const float*)d_in[22];
    const float* db1  = (const float*)d_in[23];
    const float* dW2  = (const float*)d_in[24];
    const float* db2  = (const float*)d_in[25];
    const float* dWr  = (const float*)d_in[26];
    const float* dbr  = (const float*)d_in[27];
    const float* lng  = (const float*)d_in[28];
    const float* lnb  = (const float*)d_in[29];
    float* ws  = (float*)d_ws;
    float* out = (float*)d_out;

    hipMemsetAsync((char*)d_ws + (size_t)WS_COUNTS * 4, 0, 512 * 4, stream);
    k_prep<<<48, TPB, 0, stream>>>(Wq, Wk, Wv, cb, ws);
    k_stats<<<N_, TPB, 0, stream>>>(x, ws);
    k_embed<<<(M_ * D_) / TPB, TPB, 0, stream>>>(x, rw, rb, inpW, inpb, ws);
    k_attn<<<N_ * 4, TPB, 0, stream>>>(ws, bq, bk, bv);
    k_woffn<<<M_ / 64, TPB, 0, stream>>>(ws, Wo, bo, g1, b1, fW1, fb1, fW2, fb2, g2, b2);
    k_quant<<<M_ / QROWS, TPB, 0, stream>>>(ws, cb, out);
    k_dec<<<M_ / DR_, TPB, 0, stream>>>(ws, x, cb, dW1, db1, dW2, db2, dWr, dbr, lng, lnb, rw, rb, out);
    k_final<<<1, TPB, 0, stream>>>(ws, out);
}

// Round 11
// 670.111 us; speedup vs baseline: 1.1957x; 1.0630x over previous
//
#include <hip/hip_runtime.h>
#include <math.h>

#define TPB 256

// problem dims
#define B_  32
#define L_  2048
#define C_  32
#define PL_ 16
#define P_  128
#define D_  64
#define HE_ 256
#define HD_ 256
#define K_  512
#define N_  1024      // B*C
#define M_  131072    // N_*P_

#define EPS_  1e-5f
#define BETA_ 0.25f
#define CW_   0.2f

// output offsets (floats). order: loss_total, rec_loss, z_q_st, r, indices, perplexity
#define OUT_LOSS 0
#define OUT_REC  1
#define OUT_ZQ   2
#define OUT_R    8388610      // 2 + M_*D_
#define OUT_IDX  10485762     // OUT_R + B_*L_*C_
#define OUT_PERP 10616834     // OUT_IDX + M_

// workspace offsets (floats)
#define WS_MEAN   0
#define WS_STD    1024
#define WS_QT     2048        // WqT [64 t][64 j]
#define WS_KT     6144        // WkT
#define WS_VT     10240       // WvT
#define WS_E2     34816
#define WS_COUNTS 35328
#define WS_CPART  35840       // 1024 entries, ends at 36864
#define WS_H0     36864
#define WS_H1     8425472     // WS_H0 + M_*D_  (AO; dead after k_woffn -> RPART scratch)
#define WS_RPART  WS_H1

// ---------------- prep: transposes (Wq, Wk, Wv) + codebook e2 ----------------
__global__ void k_prep(const float* __restrict__ Wq, const float* __restrict__ Wk,
                       const float* __restrict__ Wv,
                       const float* __restrict__ cb, float* __restrict__ ws) {
    int g = blockIdx.x * TPB + threadIdx.x;
    if (g < 4096) { int t = g >> 6, j = g & 63; ws[WS_QT + g] = Wq[j * D_ + t]; }
    else if (g < 8192) { int g2 = g - 4096; int t = g2 >> 6, j = g2 & 63; ws[WS_KT + g2] = Wk[j * D_ + t]; }
    else if (g < 12288) { int g2 = g - 8192; int t = g2 >> 6, j = g2 & 63; ws[WS_VT + g2] = Wv[j * D_ + t]; }
    if (g < K_) {
        float s = 0.f;
        for (int j = 0; j < D_; j++) { float v = cb[g * D_ + j]; s += v * v; }
        ws[WS_E2 + g] = s;
    }
}

// ---------------- RevIN stats: 4 channels per block, float4 loads ----------------
__global__ void k_stats(const float* __restrict__ x, float* __restrict__ ws) {
    const int blk = blockIdx.x;             // 256 blocks
    const int b = blk >> 3, c0 = (blk & 7) * 4;
    const float4* xp = (const float4*)(x + (size_t)b * L_ * C_ + c0);
    float4 s = {0.f, 0.f, 0.f, 0.f}, s2 = {0.f, 0.f, 0.f, 0.f};
    for (int l = threadIdx.x; l < L_; l += TPB) {
        float4 v = xp[(size_t)l * 8];       // row stride C_/4 = 8 float4
        s.x += v.x; s.y += v.y; s.z += v.z; s.w += v.w;
        s2.x += v.x * v.x; s2.y += v.y * v.y; s2.z += v.z * v.z; s2.w += v.w * v.w;
    }
    __shared__ float4 sh[TPB], sh2[TPB];
    sh[threadIdx.x] = s; sh2[threadIdx.x] = s2; __syncthreads();
    for (int o2 = 128; o2 > 0; o2 >>= 1) {
        if (threadIdx.x < o2) {
            float4 a = sh[threadIdx.x], bq_ = sh[threadIdx.x + o2];
            a.x += bq_.x; a.y += bq_.y; a.z += bq_.z; a.w += bq_.w; sh[threadIdx.x] = a;
            float4 a2 = sh2[threadIdx.x], b2_ = sh2[threadIdx.x + o2];
            a2.x += b2_.x; a2.y += b2_.y; a2.z += b2_.z; a2.w += b2_.w; sh2[threadIdx.x] = a2;
        }
        __syncthreads();
    }
    if (threadIdx.x == 0) {
        float sv[4] = {sh[0].x, sh[0].y, sh[0].z, sh[0].w};
        float qv[4] = {sh2[0].x, sh2[0].y, sh2[0].z, sh2[0].w};
#pragma unroll
        for (int u = 0; u < 4; u++) {
            float m = sv[u] / (float)L_;
            float var = qv[u] / (float)L_ - m * m;
            ws[WS_MEAN + b * 32 + c0 + u] = m;
            ws[WS_STD + b * 32 + c0 + u] = sqrtf(var + EPS_);
        }
    }
}

// ---------------- patchify + input embedding (float4 of d per thread) ----------------
__global__ __launch_bounds__(TPB) void k_embed(
    const float* __restrict__ x, const float* __restrict__ rw, const float* __restrict__ rb,
    const float* __restrict__ inpW, const float* __restrict__ inpb, float* __restrict__ ws) {
    int g = blockIdx.x * TPB + threadIdx.x;            // < M_*16
    int row = g >> 4, d4 = g & 15;
    int n = row >> 7, p = row & 127;
    int b = n >> 5, c = n & 31;
    float m = ws[WS_MEAN + n], sd = ws[WS_STD + n];
    float w = rw[c], bb = rb[c];
    const float* xp = x + (size_t)b * L_ * C_ + (size_t)p * PL_ * C_ + c;
    const float4* W4 = (const float4*)inpW;
    float4 acc = ((const float4*)inpb)[d4];
#pragma unroll
    for (int j = 0; j < PL_; j++) {
        float xv = xp[(size_t)j * C_];
        float xn = (xv - m) / sd * w + bb;
        float4 wv = W4[j * 16 + d4];
        acc.x += xn * wv.x; acc.y += xn * wv.y; acc.z += xn * wv.z; acc.w += xn * wv.w;
    }
    ((float4*)(ws + WS_H0))[g] = acc;
}

// ---------------- attention v11: v10 + XCD-aware block swizzle ----------------
#define HSS  68         // hs row stride
#define HS_  0          // 128*68 = 8704
#define KH_  8704       // 128*16 = 2048
#define VH_  10752      // 2048
#define SMF  12800      // 51200 bytes

__global__ __launch_bounds__(TPB) void k_attn(
    float* __restrict__ ws,
    const float* __restrict__ bq, const float* __restrict__ bk, const float* __restrict__ bv) {
    __shared__ float sm[SMF];
    const int tid = threadIdx.x;
    // XCD swizzle: 8 XCDs round-robin on blockIdx; keep a seq's 4 head-blocks on one XCD.
    const int xcd = blockIdx.x & 7, iw = blockIdx.x >> 3;
    const int n = xcd * 128 + (iw >> 2), hh = iw & 3;
    const float* h0 = ws + WS_H0 + (size_t)n * (P_ * D_);
    float* agl = ws + WS_H1 + (size_t)n * (P_ * D_);   // AO output

    // stage hs
    {
        const float4* h04 = (const float4*)h0;
#pragma unroll
        for (int it = 0; it < 8; ++it) {
            int e = tid + it * 256;
            int r = e >> 4, j4 = e & 15;
            *(float4*)(sm + HS_ + r * HSS + j4 * 4) = h04[e];
        }
    }
    __syncthreads();

    const int t_ = tid & 15, ib = tid >> 4;
    const float4* WqT4 = (const float4*)(ws + WS_QT);
    const float4* WkT4 = (const float4*)(ws + WS_KT);
    const float4* WvT4 = (const float4*)(ws + WS_VT);

    // ---- fused K+V: thread owns dim t_, rows ib+16*it; each h4 read once ----
    {
        float4 wk[16], wv[16];
        const float4* kr = WkT4 + (size_t)(hh * 16 + t_) * 16;
        const float4* vr = WvT4 + (size_t)(hh * 16 + t_) * 16;
#pragma unroll
        for (int j4 = 0; j4 < 16; j4++) { wk[j4] = kr[j4]; wv[j4] = vr[j4]; }
        float bbk = bk[hh * 16 + t_], bbv = bv[hh * 16 + t_];
#pragma unroll
        for (int it = 0; it < 8; it++) {
            int i2 = ib + it * 16;
            const float4* hr = (const float4*)(sm + HS_ + i2 * HSS);
            float accK = bbk, accV = bbv;
#pragma unroll
            for (int j4 = 0; j4 < 16; j4++) {
                float4 h4 = hr[j4];
                float4 k4 = wk[j4], v4 = wv[j4];
                accK += h4.x * k4.x + h4.y * k4.y + h4.z * k4.z + h4.w * k4.w;
                accV += h4.x * v4.x + h4.y * v4.y + h4.z * v4.z + h4.w * v4.w;
            }
            sm[KH_ + i2 * 16 + t_] = accK;
            sm[VH_ + i2 * 16 + t_] = accV;
        }
    }
    // ---- q: pair (row i, half) computes 8 dims from LDS hs, exchange -> full q ----
    const int i = tid >> 1, half = tid & 1;
    float q0[8], q1[8];
    {
        float4 hreg[16];
        const float4* hr = (const float4*)(sm + HS_ + i * HSS);
#pragma unroll
        for (int j4 = 0; j4 < 16; j4++) hreg[j4] = hr[j4];
        float qh[8];
#pragma unroll
        for (int u = 0; u < 8; u++) {
            const float4* wr = WqT4 + (size_t)(hh * 16 + half * 8 + u) * 16;
            float acc = bq[hh * 16 + half * 8 + u];
#pragma unroll
            for (int j4 = 0; j4 < 16; j4++) {
                float4 w4 = wr[j4];
                acc += hreg[j4].x * w4.x + hreg[j4].y * w4.y + hreg[j4].z * w4.z + hreg[j4].w * w4.w;
            }
            qh[u] = acc;
        }
#pragma unroll
        for (int u = 0; u < 8; u++) {
            float oth = __shfl_xor(qh[u], 1);
            q0[u] = half ? oth : qh[u];
            q1[u] = half ? qh[u] : oth;
        }
    }
    __syncthreads();   // kh/vh ready
    // ---- max-free single-pass softmax over parity keys (scores |s|<<1) ----
    float S = 0.f;
    float o[16];
#pragma unroll
    for (int u = 0; u < 16; u++) o[u] = 0.f;
    const float4* kh4 = (const float4*)(sm + KH_);
    const float4* vh4 = (const float4*)(sm + VH_);
#pragma unroll 4
    for (int m2 = 0; m2 < 64; m2++) {
        int m = m2 * 2 + half;
        float4 a0 = kh4[m * 4 + 0], a1 = kh4[m * 4 + 1], a2 = kh4[m * 4 + 2], a3 = kh4[m * 4 + 3];
        float sp = q0[0] * a0.x + q0[1] * a0.y + q0[2] * a0.z + q0[3] * a0.w
                 + q0[4] * a1.x + q0[5] * a1.y + q0[6] * a1.z + q0[7] * a1.w
                 + q1[0] * a2.x + q1[1] * a2.y + q1[2] * a2.z + q1[3] * a2.w
                 + q1[4] * a3.x + q1[5] * a3.y + q1[6] * a3.z + q1[7] * a3.w;
        float p = __expf(sp * 0.25f);   // exact softmax: max-shift unnecessary at this scale
        S += p;
        float4 v0 = vh4[m * 4 + 0], v1 = vh4[m * 4 + 1], v2 = vh4[m * 4 + 2], v3 = vh4[m * 4 + 3];
        o[0] += p * v0.x; o[1] += p * v0.y; o[2] += p * v0.z; o[3] += p * v0.w;
        o[4] += p * v1.x; o[5] += p * v1.y; o[6] += p * v1.z; o[7] += p * v1.w;
        o[8] += p * v2.x; o[9] += p * v2.y; o[10] += p * v2.z; o[11] += p * v2.w;
        o[12] += p * v3.x; o[13] += p * v3.y; o[14] += p * v3.z; o[15] += p * v3.w;
    }
    // ---- merge pair (pure add) ----
    {
        S += __shfl_xor(S, 1);
        float inv = 1.f / S;
        float wv[8];
#pragma unroll
        for (int u = 0; u < 8; u++) {
            float lo = o[u] + __shfl_xor(o[u], 1);
            float hi = o[8 + u] + __shfl_xor(o[8 + u], 1);
            wv[u] = (half ? hi : lo) * inv;
        }
        float4 r0, r1;
        r0.x = wv[0]; r0.y = wv[1]; r0.z = wv[2]; r0.w = wv[3];
        r1.x = wv[4]; r1.y = wv[5]; r1.z = wv[6]; r1.w = wv[7];
        float4* ap4 = (float4*)(agl + (size_t)i * D_ + hh * 16 + half * 8);
        ap4[0] = r0; ap4[1] = r1;
    }
}

// ---------------- fused Wo+LN1+FFN+LN2: AO -> z, no h1 round-trip ----------------
#define FHS  68

__global__ __launch_bounds__(TPB) void k_woffn(
    float* __restrict__ ws, const float* __restrict__ Wo, const float* __restrict__ bo,
    const float* __restrict__ g1, const float* __restrict__ b1,
    const float* __restrict__ fW1, const float* __restrict__ fb1,
    const float* __restrict__ fW2, const float* __restrict__ fb2,
    const float* __restrict__ g2, const float* __restrict__ b2) {
    __shared__ float bufA[64][FHS];   // aoT in phase A, Hc in phase B
    __shared__ float hT[64][FHS];     // h1 transposed [d][row]
    const int tid = threadIdx.x;
    const int row0 = blockIdx.x * 64;
    const float* aog = ws + WS_H1 + (size_t)row0 * D_;

    // stage aoT
    {
        const float4* ao4 = (const float4*)aog;
#pragma unroll
        for (int it = 0; it < 4; ++it) {
            int e = tid + it * 256;
            int r = e >> 4, j4 = e & 15;
            float4 v = ao4[e];
            bufA[j4 * 4 + 0][r] = v.x; bufA[j4 * 4 + 1][r] = v.y;
            bufA[j4 * 4 + 2][r] = v.z; bufA[j4 * 4 + 3][r] = v.w;
        }
    }
    const int ty = tid >> 4, tx = tid & 15;
    // ---- phase A: Wo GEMM ----
    float acc[4][4];
    {
        float4 bb = ((const float4*)bo)[tx];
#pragma unroll
        for (int r = 0; r < 4; r++) { acc[r][0] = bb.x; acc[r][1] = bb.y; acc[r][2] = bb.z; acc[r][3] = bb.w; }
    }
    __syncthreads();
    const float4* Wo4 = (const float4*)Wo;
#pragma unroll 4
    for (int j = 0; j < 64; ++j) {
        float4 a = *(const float4*)&bufA[j][ty * 4];
        float4 w = Wo4[j * 16 + tx];
        float ar[4] = {a.x, a.y, a.z, a.w}, wr[4] = {w.x, w.y, w.z, w.w};
#pragma unroll
        for (int r = 0; r < 4; r++)
#pragma unroll
            for (int c = 0; c < 4; c++) acc[r][c] += ar[r] * wr[c];
    }
    // residual + LN1 -> h1v (kept in regs)
    float h1v[4][4];
    {
        const float4* h04 = (const float4*)(ws + WS_H0 + (size_t)row0 * D_);
        float4 gg = ((const float4*)g1)[tx], bbn = ((const float4*)b1)[tx];
#pragma unroll
        for (int r = 0; r < 4; r++) {
            float4 res = h04[(ty * 4 + r) * 16 + tx];
            acc[r][0] += res.x; acc[r][1] += res.y; acc[r][2] += res.z; acc[r][3] += res.w;
            float s = acc[r][0] + acc[r][1] + acc[r][2] + acc[r][3];
            s += __shfl_xor(s, 1); s += __shfl_xor(s, 2); s += __shfl_xor(s, 4); s += __shfl_xor(s, 8);
            float mean_ = s * (1.f / 64.f);
            float vv = 0.f;
#pragma unroll
            for (int c = 0; c < 4; c++) { float d_ = acc[r][c] - mean_; vv += d_ * d_; }
            vv += __shfl_xor(vv, 1); vv += __shfl_xor(vv, 2); vv += __shfl_xor(vv, 4); vv += __shfl_xor(vv, 8);
            float rstd = 1.f / sqrtf(vv * (1.f / 64.f) + EPS_);
            h1v[r][0] = (acc[r][0] - mean_) * rstd * gg.x + bbn.x;
            h1v[r][1] = (acc[r][1] - mean_) * rstd * gg.y + bbn.y;
            h1v[r][2] = (acc[r][2] - mean_) * rstd * gg.z + bbn.z;
            h1v[r][3] = (acc[r][3] - mean_) * rstd * gg.w + bbn.w;
        }
    }
    // scatter h1 into hT[d][row]
#pragma unroll
    for (int r = 0; r < 4; r++)
#pragma unroll
        for (int c = 0; c < 4; c++) hT[tx * 4 + c][ty * 4 + r] = h1v[r][c];
    // ---- phase B: FFN GEMMs (Hc aliases bufA) ----
    const float4* W14 = (const float4*)fW1;
    const float4* W24 = (const float4*)fW2;
    float outv[4][4];
    {
        float4 bb = ((const float4*)fb2)[tx];
#pragma unroll
        for (int r = 0; r < 4; r++) { outv[r][0] = bb.x; outv[r][1] = bb.y; outv[r][2] = bb.z; outv[r][3] = bb.w; }
    }
    __syncthreads();   // hT ready; all aoT reads done -> bufA reusable

    for (int tc = 0; tc < 4; ++tc) {
        float a2[4][4];
        {
            float4 bb1 = ((const float4*)fb1)[tc * 16 + tx];
#pragma unroll
            for (int r = 0; r < 4; r++) { a2[r][0] = bb1.x; a2[r][1] = bb1.y; a2[r][2] = bb1.z; a2[r][3] = bb1.w; }
        }
#pragma unroll 4
        for (int j = 0; j < 64; ++j) {
            float4 a = *(const float4*)&hT[j][ty * 4];
            float4 w = W14[j * 64 + tc * 16 + tx];
            float ar[4] = {a.x, a.y, a.z, a.w}, wr[4] = {w.x, w.y, w.z, w.w};
#pragma unroll
            for (int r = 0; r < 4; r++)
#pragma unroll
                for (int c = 0; c < 4; c++) a2[r][c] += ar[r] * wr[c];
        }
        __syncthreads();   // prev Hc reads done
#pragma unroll
        for (int r = 0; r < 4; r++)
#pragma unroll
            for (int c = 0; c < 4; c++) bufA[tx * 4 + c][ty * 4 + r] = fmaxf(a2[r][c], 0.f);
        __syncthreads();
#pragma unroll 4
        for (int h = 0; h < 64; ++h) {
            float4 a = *(const float4*)&bufA[h][ty * 4];
            float4 w = W24[(tc * 64 + h) * 16 + tx];
            float ar[4] = {a.x, a.y, a.z, a.w}, wr[4] = {w.x, w.y, w.z, w.w};
#pragma unroll
            for (int r = 0; r < 4; r++)
#pragma unroll
                for (int c = 0; c < 4; c++) outv[r][c] += ar[r] * wr[c];
        }
    }
    // residual (h1v) + LN2 -> z
    {
        float4 gg = ((const float4*)g2)[tx], bb = ((const float4*)b2)[tx];
        float4* zp = (float4*)(ws + WS_H0 + (size_t)row0 * D_);
#pragma unroll
        for (int r = 0; r < 4; r++) {
            outv[r][0] += h1v[r][0]; outv[r][1] += h1v[r][1];
            outv[r][2] += h1v[r][2]; outv[r][3] += h1v[r][3];
            float s = outv[r][0] + outv[r][1] + outv[r][2] + outv[r][3];
            s += __shfl_xor(s, 1); s += __shfl_xor(s, 2); s += __shfl_xor(s, 4); s += __shfl_xor(s, 8);
            float mean_ = s * (1.f / 64.f);
            float vv = 0.f;
#pragma unroll
            for (int c = 0; c < 4; c++) { float d_ = outv[r][c] - mean_; vv += d_ * d_; }
            vv += __shfl_xor(vv, 1); vv += __shfl_xor(vv, 2); vv += __shfl_xor(vv, 4); vv += __shfl_xor(vv, 8);
            float rstd = 1.f / sqrtf(vv * (1.f / 64.f) + EPS_);
            float4 z;
            z.x = (outv[r][0] - mean_) * rstd * gg.x + bb.x;
            z.y = (outv[r][1] - mean_) * rstd * gg.y + bb.y;
            z.z = (outv[r][2] - mean_) * rstd * gg.z + bb.z;
            z.w = (outv[r][3] - mean_) * rstd * gg.w + bb.w;
            zp[(ty * 4 + r) * 16 + tx] = z;
        }
    }
}

// ---------------- quantizer: LDS-tiled register-blocked distance GEMM ----------------
#define QROWS 128
#define QKT   64
#define ZTS   132
#define CBS   68

__global__ __launch_bounds__(TPB) void k_quant(
    float* __restrict__ ws, const float* __restrict__ cb, float* __restrict__ out) {
    __shared__ float zT[64][ZTS];
    __shared__ float cbT[64][CBS];
    __shared__ float z2s[QROWS];
    __shared__ float e2t[QKT];
    __shared__ int   ridx[QROWS];
    __shared__ float red[TPB];

    const int tid = threadIdx.x;
    const int row0 = blockIdx.x * QROWS;
    const float* zg = ws + WS_H0 + (size_t)row0 * D_;
    const float4* zg4 = (const float4*)zg;
    const float4* cbg4 = (const float4*)cb;

    {
        int j4 = tid >> 4;
#pragma unroll
        for (int it = 0; it < 8; ++it) {
            int r = (tid & 15) + it * 16;
            float4 v = zg4[r * 16 + j4];
            zT[j4 * 4 + 0][r] = v.x; zT[j4 * 4 + 1][r] = v.y;
            zT[j4 * 4 + 2][r] = v.z; zT[j4 * 4 + 3][r] = v.w;
        }
    }
    if (tid < QROWS) {
        const float4* zr = (const float4*)(zg + (size_t)tid * D_);
        float s = 0.f;
#pragma unroll
        for (int j = 0; j < 16; j++) { float4 v = zr[j]; s += v.x * v.x + v.y * v.y + v.z * v.z + v.w * v.w; }
        z2s[tid] = s;
    }

    const int ty = tid >> 4, tx = tid & 15;
    float best[8]; int bidx[8];
#pragma unroll
    for (int u = 0; u < 8; u++) { best[u] = 3.4e38f; bidx[u] = 0; }

    for (int t = 0; t < K_ / QKT; ++t) {
        const int k0 = t * QKT;
        __syncthreads();
        {
            int j4 = tid >> 4;
#pragma unroll
            for (int it = 0; it < 4; ++it) {
                int kk = (tid & 15) + it * 16;
                float4 v = cbg4[(size_t)(k0 + kk) * 16 + j4];
                cbT[j4 * 4 + 0][kk] = v.x; cbT[j4 * 4 + 1][kk] = v.y;
                cbT[j4 * 4 + 2][kk] = v.z; cbT[j4 * 4 + 3][kk] = v.w;
            }
        }
        if (tid < QKT) e2t[tid] = ws[WS_E2 + k0 + tid];
        __syncthreads();

        float acc[8][4];
#pragma unroll
        for (int u = 0; u < 8; u++)
#pragma unroll
            for (int c = 0; c < 4; c++) acc[u][c] = 0.f;

        for (int j = 0; j < 64; ++j) {
            float4 a0 = *(const float4*)&zT[j][ty * 8];
            float4 a1 = *(const float4*)&zT[j][ty * 8 + 4];
            float4 b0 = *(const float4*)&cbT[j][tx * 4];
            float ar[8] = {a0.x, a0.y, a0.z, a0.w, a1.x, a1.y, a1.z, a1.w};
            float br[4] = {b0.x, b0.y, b0.z, b0.w};
#pragma unroll
            for (int u = 0; u < 8; u++)
#pragma unroll
                for (int c = 0; c < 4; c++) acc[u][c] += ar[u] * br[c];
        }

#pragma unroll
        for (int u = 0; u < 8; u++) {
            float z2v = z2s[ty * 8 + u];
#pragma unroll
            for (int c = 0; c < 4; c++) {
                float dist = (z2v + e2t[tx * 4 + c]) - 2.f * acc[u][c];
                int kidx = k0 + tx * 4 + c;
                if (dist < best[u]) { best[u] = dist; bidx[u] = kidx; }
            }
        }
    }

#pragma unroll
    for (int m = 1; m <= 8; m <<= 1) {
#pragma unroll
        for (int u = 0; u < 8; u++) {
            float ob = __shfl_xor(best[u], m, 64);
            int oi = __shfl_xor(bidx[u], m, 64);
            if (ob < best[u] || (ob == best[u] && oi < bidx[u])) { best[u] = ob; bidx[u] = oi; }
        }
    }
    if (tx == 0) {
#pragma unroll
        for (int u = 0; u < 8; u++) ridx[ty * 8 + u] = bidx[u];
    }
    __syncthreads();

    if (tid < QROWS) {
        int bi = ridx[tid];
        out[OUT_IDX + row0 + tid] = (float)bi;
        atomicAdd((unsigned int*)ws + WS_COUNTS + bi, 1u);
    }
    {
        int r = tid >> 1, half = tid & 1;
        int bi = ridx[r];
        const float4* cw = (const float4*)(cb + (size_t)bi * D_ + half * 32);
        const float4* zr4 = (const float4*)(zg + (size_t)r * D_ + half * 32);
        float2* zqo = (float2*)(out + OUT_ZQ + (size_t)(row0 + r) * D_ + half * 32);
        float csum = 0.f;
#pragma unroll
        for (int j4 = 0; j4 < 8; ++j4) {
            float4 w = cw[j4]; float4 zz = zr4[j4];
            float d0 = w.x - zz.x, d1 = w.y - zz.y, d2 = w.z - zz.z, d3 = w.w - zz.w;
            csum += d0 * d0 + d1 * d1 + d2 * d2 + d3 * d3;
            float2 p0; p0.x = w.x; p0.y = w.y; zqo[j4 * 2] = p0;
            float2 p1; p1.x = w.z; p1.y = w.w; zqo[j4 * 2 + 1] = p1;
        }
        red[tid] = csum;
    }
    __syncthreads();
    for (int o2 = 128; o2 > 0; o2 >>= 1) {
        if (tid < o2) red[tid] += red[tid + o2];
        __syncthreads();
    }
    if (tid == 0) ws[WS_CPART + blockIdx.x] = red[0];
}

// ---------------- decoder: LDS-tiled GEMM + LN + denorm + rec-loss ----------------
#define DR_ 64

__global__ __launch_bounds__(TPB) void k_dec(
    float* __restrict__ ws, const float* __restrict__ x, const float* __restrict__ cb,
    const float* __restrict__ dW1, const float* __restrict__ db1,
    const float* __restrict__ dW2, const float* __restrict__ db2,
    const float* __restrict__ dWr, const float* __restrict__ dbr,
    const float* __restrict__ lng, const float* __restrict__ lnb,
    const float* __restrict__ rw, const float* __restrict__ rb,
    float* __restrict__ out) {
    __shared__ float zqT[64][FHS];
    __shared__ float Hc[64][FHS];
    __shared__ int   ridx[DR_];
    __shared__ float red[TPB];
    const int tid = threadIdx.x;
    const int row0 = blockIdx.x * DR_;
    if (tid < DR_) ridx[tid] = (int)out[OUT_IDX + row0 + tid];
    __syncthreads();
    {
        const float4* cb4 = (const float4*)cb;
#pragma unroll
        for (int it = 0; it < 4; ++it) {
            int e = tid + it * 256;
            int r = e >> 4, j4 = e & 15;
            float4 v = cb4[(size_t)ridx[r] * 16 + j4];
            zqT[j4 * 4 + 0][r] = v.x; zqT[j4 * 4 + 1][r] = v.y;
            zqT[j4 * 4 + 2][r] = v.z; zqT[j4 * 4 + 3][r] = v.w;
        }
    }
    const int ty = tid >> 4, tx = tid & 15;
    const float4* dW14 = (const float4*)dW1;
    float out4[4];
    {
        float b0 = db2[tx] + dbr[tx];
#pragma unroll
        for (int r = 0; r < 4; r++) out4[r] = b0;
    }
    __syncthreads();

    for (int tc = 0; tc < 4; ++tc) {
        float acc[4][4];
        {
            float4 bb1 = ((const float4*)db1)[tc * 16 + tx];
#pragma unroll
            for (int r = 0; r < 4; r++) { acc[r][0] = bb1.x; acc[r][1] = bb1.y; acc[r][2] = bb1.z; acc[r][3] = bb1.w; }
        }
#pragma unroll 4
        for (int j = 0; j < 64; ++j) {
            float4 a = *(const float4*)&zqT[j][ty * 4];
            float4 w = dW14[j * 64 + tc * 16 + tx];
            float ar[4] = {a.x, a.y, a.z, a.w}, wr[4] = {w.x, w.y, w.z, w.w};
#pragma unroll
            for (int r = 0; r < 4; r++)
#pragma unroll
                for (int c = 0; c < 4; c++) acc[r][c] += ar[r] * wr[c];
        }
        __syncthreads();
#pragma unroll
        for (int r = 0; r < 4; r++)
#pragma unroll
            for (int c = 0; c < 4; c++) Hc[tx * 4 + c][ty * 4 + r] = fmaxf(acc[r][c], 0.f);
        __syncthreads();
#pragma unroll 8
        for (int h = 0; h < 64; ++h) {
            float4 a = *(const float4*)&Hc[h][ty * 4];
            float w = dW2[(tc * 64 + h) * 16 + tx];
            out4[0] += a.x * w; out4[1] += a.y * w; out4[2] += a.z * w; out4[3] += a.w * w;
        }
    }
#pragma unroll 8
    for (int j = 0; j < 64; ++j) {
        float4 a = *(const float4*)&zqT[j][ty * 4];
        float w = dWr[j * 16 + tx];
        out4[0] += a.x * w; out4[1] += a.y * w; out4[2] += a.z * w; out4[3] += a.w * w;
    }
    const int n = row0 >> 7;
    const int b = n >> 5, c = n & 31;
    const float sd = ws[WS_STD + n], mn = ws[WS_MEAN + n];
    const float inv = 1.f / (rw[c] + EPS_ * EPS_);
    const float rbc = rb[c];
    const float lg = lng[tx], lb = lnb[tx];
    float part = 0.f;
#pragma unroll
    for (int r = 0; r < 4; r++) {
        float v = out4[r];
        float s = v;
        s += __shfl_xor(s, 1); s += __shfl_xor(s, 2); s += __shfl_xor(s, 4); s += __shfl_xor(s, 8);
        float mean_ = s * (1.f / 16.f);
        float d_ = v - mean_;
        float vv = d_ * d_;
        vv += __shfl_xor(vv, 1); vv += __shfl_xor(vv, 2); vv += __shfl_xor(vv, 4); vv += __shfl_xor(vv, 8);
        float rstd = 1.f / sqrtf(vv * (1.f / 16.f) + EPS_);
        float yv = d_ * rstd * lg + lb;
        float rr = (yv - rbc) * inv * sd + mn;
        int row = row0 + ty * 4 + r;
        int p = row & 127;
        size_t xi = (size_t)b * L_ * C_ + (size_t)(p * PL_ + tx) * C_ + c;
        out[OUT_R + xi] = rr;
        float dx = x[xi] - rr; part += dx * dx;
    }
    red[tid] = part;
    __syncthreads();
    for (int o2 = 128; o2 > 0; o2 >>= 1) {
        if (tid < o2) red[tid] += red[tid + o2];
        __syncthreads();
    }
    if (tid == 0) ws[WS_RPART + blockIdx.x] = red[0];
}

// ---------------- final scalar reductions ----------------
__global__ void k_final(float* __restrict__ ws, float* __restrict__ out) {
    __shared__ float sh[TPB];
    int tid = threadIdx.x;
    float cs = 0.f;
    for (int i2 = tid; i2 < 1024; i2 += TPB) cs += ws[WS_CPART + i2];
    sh[tid] = cs; __syncthreads();
    for (int o2 = 128; o2 > 0; o2 >>= 1) { if (tid < o2) sh[tid] += sh[tid + o2]; __syncthreads(); }
    float csum = sh[0]; __syncthreads();
    float rs = 0.f;
    for (int i2 = tid; i2 < 2048; i2 += TPB) rs += ws[WS_RPART + i2];
    sh[tid] = rs; __syncthreads();
    for (int o2 = 128; o2 > 0; o2 >>= 1) { if (tid < o2) sh[tid] += sh[tid + o2]; __syncthreads(); }
    float rsum = sh[0]; __syncthreads();
    const unsigned int* counts = (const unsigned int*)ws + WS_COUNTS;
    float H = 0.f;
    for (int k2 = tid; k2 < K_; k2 += TPB) {
        float p = (float)counts[k2] / (131072.f + EPS_);
        H += p * logf(p + EPS_);
    }
    sh[tid] = H; __syncthreads();
    for (int o2 = 128; o2 > 0; o2 >>= 1) { if (tid < o2) sh[tid] += sh[tid + o2]; __syncthreads(); }
    if (tid == 0) {
        float rec = rsum / 2097152.f;
        float msd = csum / 8388608.f;
        float cl = (1.f + BETA_) * msd;
        out[OUT_LOSS] = rec + CW_ * cl;
        out[OUT_REC] = rec;
        out[OUT_PERP] = expf(-sh[0]);
    }
}

extern "C" void kernel_launch(void* const* d_in, const int* in_sizes, int n_in,
                              void* d_out, int out_size, void* d_ws, size_t ws_size,
                              hipStream_t stream) {
    const float* x    = (const float*)d_in[0];
    const float* rw   = (const float*)d_in[1];
    const float* rb   = (const float*)d_in[2];
    const float* inpW = (const float*)d_in[3];
    const float* inpb = (const float*)d_in[4];
    const float* Wq   = (const float*)d_in[5];
    const float* bq   = (const float*)d_in[6];
    const float* Wk   = (const float*)d_in[7];
    const float* bk   = (const float*)d_in[8];
    const float* Wv   = (const float*)d_in[9];
    const float* bv   = (const float*)d_in[10];
    const float* Wo   = (const float*)d_in[11];
    const float* bo   = (const float*)d_in[12];
    const float* g1   = (const float*)d_in[13];
    const float* b1   = (const float*)d_in[14];
    const float* fW1  = (const float*)d_in[15];
    const float* fb1  = (const float*)d_in[16];
    const float* fW2  = (const float*)d_in[17];
    const float* fb2  = (const float*)d_in[18];
    const float* g2   = (const float*)d_in[19];
    const float* b2   = (const float*)d_in[20];
    const float* cb   = (const float*)d_in[21];
    const float* dW1  = (const float*)d_in[22];
    const float* db1  = (const float*)d_in[23];
    const float* dW2  = (const float*)d_in[24];
    const float* db2  = (const float*)d_in[25];
    const float* dWr  = (const float*)d_in[26];
    const float* dbr  = (const float*)d_in[27];
    const float* lng  = (const float*)d_in[28];
    const float* lnb  = (const float*)d_in[29];
    float* ws  = (float*)d_ws;
    float* out = (float*)d_out;

    hipMemsetAsync((char*)d_ws + (size_t)WS_COUNTS * 4, 0, 512 * 4, stream);
    k_prep<<<48, TPB, 0, stream>>>(Wq, Wk, Wv, cb, ws);
    k_stats<<<256, TPB, 0, stream>>>(x, ws);
    k_embed<<<(M_ * 16) / TPB, TPB, 0, stream>>>(x, rw, rb, inpW, inpb, ws);
    k_attn<<<N_ * 4, TPB, 0, stream>>>(ws, bq, bk, bv);
    k_woffn<<<M_ / 64, TPB, 0, stream>>>(ws, Wo, bo, g1, b1, fW1, fb1, fW2, fb2, g2, b2);
    k_quant<<<M_ / QROWS, TPB, 0, stream>>>(ws, cb, out);
    k_dec<<<M_ / DR_, TPB, 0, stream>>>(ws, x, cb, dW1, db1, dW2, db2, dWr, dbr, lng, lnb, rw, rb, out);
    k_final<<<1, TPB, 0, stream>>>(ws, out);
}

// Round 12
// 659.963 us; speedup vs baseline: 1.2141x; 1.0154x over previous
//
#include <hip/hip_runtime.h>
#include <math.h>

#define TPB 256

// problem dims
#define B_  32
#define L_  2048
#define C_  32
#define PL_ 16
#define P_  128
#define D_  64
#define HE_ 256
#define HD_ 256
#define K_  512
#define N_  1024      // B*C
#define M_  131072    // N_*P_

#define EPS_  1e-5f
#define BETA_ 0.25f
#define CW_   0.2f

// output offsets (floats). order: loss_total, rec_loss, z_q_st, r, indices, perplexity
#define OUT_LOSS 0
#define OUT_REC  1
#define OUT_ZQ   2
#define OUT_R    8388610      // 2 + M_*D_
#define OUT_IDX  10485762     // OUT_R + B_*L_*C_
#define OUT_PERP 10616834     // OUT_IDX + M_

// workspace offsets (floats)
#define WS_MEAN   0
#define WS_STD    1024
#define WS_QT     2048        // WqT [64 t][64 j]
#define WS_KT     6144        // WkT
#define WS_VT     10240       // WvT
#define WS_E2     34816
#define WS_COUNTS 35328
#define WS_CPART  35840       // 1024 entries, ends at 36864
#define WS_H0     36864
#define WS_H1     8425472     // WS_H0 + M_*D_  (AO; dead after k_woffn -> RPART scratch)
#define WS_RPART  WS_H1

// ---------------- prep: transposes (Wq, Wk, Wv) + codebook e2 ----------------
__global__ void k_prep(const float* __restrict__ Wq, const float* __restrict__ Wk,
                       const float* __restrict__ Wv,
                       const float* __restrict__ cb, float* __restrict__ ws) {
    int g = blockIdx.x * TPB + threadIdx.x;
    if (g < 4096) { int t = g >> 6, j = g & 63; ws[WS_QT + g] = Wq[j * D_ + t]; }
    else if (g < 8192) { int g2 = g - 4096; int t = g2 >> 6, j = g2 & 63; ws[WS_KT + g2] = Wk[j * D_ + t]; }
    else if (g < 12288) { int g2 = g - 8192; int t = g2 >> 6, j = g2 & 63; ws[WS_VT + g2] = Wv[j * D_ + t]; }
    if (g < K_) {
        float s = 0.f;
        for (int j = 0; j < D_; j++) { float v = cb[g * D_ + j]; s += v * v; }
        ws[WS_E2 + g] = s;
    }
}

// ---------------- RevIN stats: 4 channels per block, float4 loads ----------------
__global__ void k_stats(const float* __restrict__ x, float* __restrict__ ws) {
    const int blk = blockIdx.x;             // 256 blocks
    const int b = blk >> 3, c0 = (blk & 7) * 4;
    const float4* xp = (const float4*)(x + (size_t)b * L_ * C_ + c0);
    float4 s = {0.f, 0.f, 0.f, 0.f}, s2 = {0.f, 0.f, 0.f, 0.f};
    for (int l = threadIdx.x; l < L_; l += TPB) {
        float4 v = xp[(size_t)l * 8];       // row stride C_/4 = 8 float4
        s.x += v.x; s.y += v.y; s.z += v.z; s.w += v.w;
        s2.x += v.x * v.x; s2.y += v.y * v.y; s2.z += v.z * v.z; s2.w += v.w * v.w;
    }
    __shared__ float4 sh[TPB], sh2[TPB];
    sh[threadIdx.x] = s; sh2[threadIdx.x] = s2; __syncthreads();
    for (int o2 = 128; o2 > 0; o2 >>= 1) {
        if (threadIdx.x < o2) {
            float4 a = sh[threadIdx.x], bq_ = sh[threadIdx.x + o2];
            a.x += bq_.x; a.y += bq_.y; a.z += bq_.z; a.w += bq_.w; sh[threadIdx.x] = a;
            float4 a2 = sh2[threadIdx.x], b2_ = sh2[threadIdx.x + o2];
            a2.x += b2_.x; a2.y += b2_.y; a2.z += b2_.z; a2.w += b2_.w; sh2[threadIdx.x] = a2;
        }
        __syncthreads();
    }
    if (threadIdx.x == 0) {
        float sv[4] = {sh[0].x, sh[0].y, sh[0].z, sh[0].w};
        float qv[4] = {sh2[0].x, sh2[0].y, sh2[0].z, sh2[0].w};
#pragma unroll
        for (int u = 0; u < 4; u++) {
            float m = sv[u] / (float)L_;
            float var = qv[u] / (float)L_ - m * m;
            ws[WS_MEAN + b * 32 + c0 + u] = m;
            ws[WS_STD + b * 32 + c0 + u] = sqrtf(var + EPS_);
        }
    }
}

// ---------------- patchify + input embedding (float4 of d per thread) ----------------
__global__ __launch_bounds__(TPB) void k_embed(
    const float* __restrict__ x, const float* __restrict__ rw, const float* __restrict__ rb,
    const float* __restrict__ inpW, const float* __restrict__ inpb, float* __restrict__ ws) {
    int g = blockIdx.x * TPB + threadIdx.x;            // < M_*16
    int row = g >> 4, d4 = g & 15;
    int n = row >> 7, p = row & 127;
    int b = n >> 5, c = n & 31;
    float m = ws[WS_MEAN + n], sd = ws[WS_STD + n];
    float w = rw[c], bb = rb[c];
    const float* xp = x + (size_t)b * L_ * C_ + (size_t)p * PL_ * C_ + c;
    const float4* W4 = (const float4*)inpW;
    float4 acc = ((const float4*)inpb)[d4];
#pragma unroll
    for (int j = 0; j < PL_; j++) {
        float xv = xp[(size_t)j * C_];
        float xn = (xv - m) / sd * w + bb;
        float4 wv = W4[j * 16 + d4];
        acc.x += xn * wv.x; acc.y += xn * wv.y; acc.z += xn * wv.z; acc.w += xn * wv.w;
    }
    ((float4*)(ws + WS_H0))[g] = acc;
}

// ---------------- attention v12: 2-rows-per-thread flash (halved LDS traffic) ----------------
#define HSS  68         // hs row stride
#define HS_  0          // 128*68 = 8704
#define KH_  8704       // 128*16 = 2048
#define VH_  10752      // 2048
#define SMF  12800      // 51200 bytes

__global__ __launch_bounds__(TPB) void k_attn(
    float* __restrict__ ws,
    const float* __restrict__ bq, const float* __restrict__ bk, const float* __restrict__ bv) {
    __shared__ float sm[SMF];
    const int tid = threadIdx.x;
    // XCD swizzle: keep a seq's 4 head-blocks on one XCD.
    const int xcd = blockIdx.x & 7, iw = blockIdx.x >> 3;
    const int n = xcd * 128 + (iw >> 2), hh = iw & 3;
    const float* h0 = ws + WS_H0 + (size_t)n * (P_ * D_);
    float* agl = ws + WS_H1 + (size_t)n * (P_ * D_);   // AO output

    // stage hs
    {
        const float4* h04 = (const float4*)h0;
#pragma unroll
        for (int it = 0; it < 8; ++it) {
            int e = tid + it * 256;
            int r = e >> 4, j4 = e & 15;
            *(float4*)(sm + HS_ + r * HSS + j4 * 4) = h04[e];
        }
    }
    __syncthreads();

    const int t_ = tid & 15, ib = tid >> 4;
    const float4* WqT4 = (const float4*)(ws + WS_QT);
    const float4* WkT4 = (const float4*)(ws + WS_KT);
    const float4* WvT4 = (const float4*)(ws + WS_VT);

    // ---- fused K+V: thread owns dim t_, rows ib+16*it; each h4 read once ----
    {
        float4 wk[16], wv[16];
        const float4* kr = WkT4 + (size_t)(hh * 16 + t_) * 16;
        const float4* vr = WvT4 + (size_t)(hh * 16 + t_) * 16;
#pragma unroll
        for (int j4 = 0; j4 < 16; j4++) { wk[j4] = kr[j4]; wv[j4] = vr[j4]; }
        float bbk = bk[hh * 16 + t_], bbv = bv[hh * 16 + t_];
#pragma unroll
        for (int it = 0; it < 8; it++) {
            int i2 = ib + it * 16;
            const float4* hr = (const float4*)(sm + HS_ + i2 * HSS);
            float accK = bbk, accV = bbv;
#pragma unroll
            for (int j4 = 0; j4 < 16; j4++) {
                float4 h4 = hr[j4];
                float4 k4 = wk[j4], v4 = wv[j4];
                accK += h4.x * k4.x + h4.y * k4.y + h4.z * k4.z + h4.w * k4.w;
                accV += h4.x * v4.x + h4.y * v4.y + h4.z * v4.z + h4.w * v4.w;
            }
            sm[KH_ + i2 * 16 + t_] = accK;
            sm[VH_ + i2 * 16 + t_] = accV;
        }
    }
    // ---- q: 4 lanes per row-group; lane qt computes (row rg*2+(qt>>1), dims (qt&1)*8..) ----
    const int rg = tid >> 2, qt = tid & 3;
    const int rmine = qt >> 1, hmine = qt & 1;
    float qA[16], qB[16];   // full q of rows 2rg, 2rg+1
    {
        const int myrow = rg * 2 + rmine;
        float4 hreg[16];
        const float4* hr = (const float4*)(sm + HS_ + myrow * HSS);
#pragma unroll
        for (int j4 = 0; j4 < 16; j4++) hreg[j4] = hr[j4];
        float qh[8];
#pragma unroll
        for (int u = 0; u < 8; u++) {
            const float4* wr = WqT4 + (size_t)(hh * 16 + hmine * 8 + u) * 16;
            float acc = bq[hh * 16 + hmine * 8 + u];
#pragma unroll
            for (int j4 = 0; j4 < 16; j4++) {
                float4 w4 = wr[j4];
                acc += hreg[j4].x * w4.x + hreg[j4].y * w4.y + hreg[j4].z * w4.z + hreg[j4].w * w4.w;
            }
            qh[u] = acc;
        }
        // stage 1: assemble my row's full q (exchange dim-halves within lane pair)
        float qm[16];
#pragma unroll
        for (int u = 0; u < 8; u++) {
            float oth = __shfl_xor(qh[u], 1);
            qm[u] = hmine ? oth : qh[u];
            qm[8 + u] = hmine ? qh[u] : oth;
        }
        // stage 2: other row's full q via xor-2
#pragma unroll
        for (int u = 0; u < 16; u++) {
            float oth = __shfl_xor(qm[u], 2);
            qA[u] = rmine ? oth : qm[u];
            qB[u] = rmine ? qm[u] : oth;
        }
    }
    __syncthreads();   // kh/vh ready
    // ---- max-free flash: 32 keys/thread (qt-strided), each K/V read feeds 2 rows ----
    float SA = 0.f, SB = 0.f;
    float oA[16], oB[16];
#pragma unroll
    for (int u = 0; u < 16; u++) { oA[u] = 0.f; oB[u] = 0.f; }
    const float4* kh4 = (const float4*)(sm + KH_);
    const float4* vh4 = (const float4*)(sm + VH_);
#pragma unroll 4
    for (int k = 0; k < 32; k++) {
        int m = k * 4 + qt;
        float4 a0 = kh4[m * 4 + 0], a1 = kh4[m * 4 + 1], a2 = kh4[m * 4 + 2], a3 = kh4[m * 4 + 3];
        float sA = qA[0] * a0.x + qA[1] * a0.y + qA[2] * a0.z + qA[3] * a0.w
                 + qA[4] * a1.x + qA[5] * a1.y + qA[6] * a1.z + qA[7] * a1.w
                 + qA[8] * a2.x + qA[9] * a2.y + qA[10] * a2.z + qA[11] * a2.w
                 + qA[12] * a3.x + qA[13] * a3.y + qA[14] * a3.z + qA[15] * a3.w;
        float sB = qB[0] * a0.x + qB[1] * a0.y + qB[2] * a0.z + qB[3] * a0.w
                 + qB[4] * a1.x + qB[5] * a1.y + qB[6] * a1.z + qB[7] * a1.w
                 + qB[8] * a2.x + qB[9] * a2.y + qB[10] * a2.z + qB[11] * a2.w
                 + qB[12] * a3.x + qB[13] * a3.y + qB[14] * a3.z + qB[15] * a3.w;
        float pA = __expf(sA * 0.25f);   // scores tiny: exact softmax w/o max-shift
        float pB = __expf(sB * 0.25f);
        SA += pA; SB += pB;
        float4 v0 = vh4[m * 4 + 0], v1 = vh4[m * 4 + 1], v2 = vh4[m * 4 + 2], v3 = vh4[m * 4 + 3];
        oA[0] += pA * v0.x; oA[1] += pA * v0.y; oA[2] += pA * v0.z; oA[3] += pA * v0.w;
        oA[4] += pA * v1.x; oA[5] += pA * v1.y; oA[6] += pA * v1.z; oA[7] += pA * v1.w;
        oA[8] += pA * v2.x; oA[9] += pA * v2.y; oA[10] += pA * v2.z; oA[11] += pA * v2.w;
        oA[12] += pA * v3.x; oA[13] += pA * v3.y; oA[14] += pA * v3.z; oA[15] += pA * v3.w;
        oB[0] += pB * v0.x; oB[1] += pB * v0.y; oB[2] += pB * v0.z; oB[3] += pB * v0.w;
        oB[4] += pB * v1.x; oB[5] += pB * v1.y; oB[6] += pB * v1.z; oB[7] += pB * v1.w;
        oB[8] += pB * v2.x; oB[9] += pB * v2.y; oB[10] += pB * v2.z; oB[11] += pB * v2.w;
        oB[12] += pB * v3.x; oB[13] += pB * v3.y; oB[14] += pB * v3.z; oB[15] += pB * v3.w;
    }
    // ---- merge across 4-lane group (pure adds), write my (row, dim-half) slice ----
    {
        SA += __shfl_xor(SA, 1); SA += __shfl_xor(SA, 2);
        SB += __shfl_xor(SB, 1); SB += __shfl_xor(SB, 2);
        float invA = 1.f / SA, invB = 1.f / SB;
#pragma unroll
        for (int u = 0; u < 16; u++) {
            oA[u] += __shfl_xor(oA[u], 1); oA[u] += __shfl_xor(oA[u], 2);
            oB[u] += __shfl_xor(oB[u], 1); oB[u] += __shfl_xor(oB[u], 2);
        }
        const int myrow = rg * 2 + rmine;
        float inv = rmine ? invB : invA;
        float wv[8];
#pragma unroll
        for (int u = 0; u < 8; u++) {
            float va = oA[hmine * 8 + u], vb = oB[hmine * 8 + u];
            wv[u] = (rmine ? vb : va) * inv;
        }
        float4 r0, r1;
        r0.x = wv[0]; r0.y = wv[1]; r0.z = wv[2]; r0.w = wv[3];
        r1.x = wv[4]; r1.y = wv[5]; r1.z = wv[6]; r1.w = wv[7];
        float4* ap4 = (float4*)(agl + (size_t)myrow * D_ + hh * 16 + hmine * 8);
        ap4[0] = r0; ap4[1] = r1;
    }
}

// ---------------- fused Wo+LN1+FFN+LN2: AO -> z, no h1 round-trip ----------------
#define FHS  68

__global__ __launch_bounds__(TPB) void k_woffn(
    float* __restrict__ ws, const float* __restrict__ Wo, const float* __restrict__ bo,
    const float* __restrict__ g1, const float* __restrict__ b1,
    const float* __restrict__ fW1, const float* __restrict__ fb1,
    const float* __restrict__ fW2, const float* __restrict__ fb2,
    const float* __restrict__ g2, const float* __restrict__ b2) {
    __shared__ float bufA[64][FHS];   // aoT in phase A, Hc in phase B
    __shared__ float hT[64][FHS];     // h1 transposed [d][row]
    const int tid = threadIdx.x;
    const int row0 = blockIdx.x * 64;
    const float* aog = ws + WS_H1 + (size_t)row0 * D_;

    // stage aoT
    {
        const float4* ao4 = (const float4*)aog;
#pragma unroll
        for (int it = 0; it < 4; ++it) {
            int e = tid + it * 256;
            int r = e >> 4, j4 = e & 15;
            float4 v = ao4[e];
            bufA[j4 * 4 + 0][r] = v.x; bufA[j4 * 4 + 1][r] = v.y;
            bufA[j4 * 4 + 2][r] = v.z; bufA[j4 * 4 + 3][r] = v.w;
        }
    }
    const int ty = tid >> 4, tx = tid & 15;
    // ---- phase A: Wo GEMM ----
    float acc[4][4];
    {
        float4 bb = ((const float4*)bo)[tx];
#pragma unroll
        for (int r = 0; r < 4; r++) { acc[r][0] = bb.x; acc[r][1] = bb.y; acc[r][2] = bb.z; acc[r][3] = bb.w; }
    }
    __syncthreads();
    const float4* Wo4 = (const float4*)Wo;
#pragma unroll 4
    for (int j = 0; j < 64; ++j) {
        float4 a = *(const float4*)&bufA[j][ty * 4];
        float4 w = Wo4[j * 16 + tx];
        float ar[4] = {a.x, a.y, a.z, a.w}, wr[4] = {w.x, w.y, w.z, w.w};
#pragma unroll
        for (int r = 0; r < 4; r++)
#pragma unroll
            for (int c = 0; c < 4; c++) acc[r][c] += ar[r] * wr[c];
    }
    // residual + LN1 -> h1v (kept in regs)
    float h1v[4][4];
    {
        const float4* h04 = (const float4*)(ws + WS_H0 + (size_t)row0 * D_);
        float4 gg = ((const float4*)g1)[tx], bbn = ((const float4*)b1)[tx];
#pragma unroll
        for (int r = 0; r < 4; r++) {
            float4 res = h04[(ty * 4 + r) * 16 + tx];
            acc[r][0] += res.x; acc[r][1] += res.y; acc[r][2] += res.z; acc[r][3] += res.w;
            float s = acc[r][0] + acc[r][1] + acc[r][2] + acc[r][3];
            s += __shfl_xor(s, 1); s += __shfl_xor(s, 2); s += __shfl_xor(s, 4); s += __shfl_xor(s, 8);
            float mean_ = s * (1.f / 64.f);
            float vv = 0.f;
#pragma unroll
            for (int c = 0; c < 4; c++) { float d_ = acc[r][c] - mean_; vv += d_ * d_; }
            vv += __shfl_xor(vv, 1); vv += __shfl_xor(vv, 2); vv += __shfl_xor(vv, 4); vv += __shfl_xor(vv, 8);
            float rstd = 1.f / sqrtf(vv * (1.f / 64.f) + EPS_);
            h1v[r][0] = (acc[r][0] - mean_) * rstd * gg.x + bbn.x;
            h1v[r][1] = (acc[r][1] - mean_) * rstd * gg.y + bbn.y;
            h1v[r][2] = (acc[r][2] - mean_) * rstd * gg.z + bbn.z;
            h1v[r][3] = (acc[r][3] - mean_) * rstd * gg.w + bbn.w;
        }
    }
    // scatter h1 into hT[d][row]
#pragma unroll
    for (int r = 0; r < 4; r++)
#pragma unroll
        for (int c = 0; c < 4; c++) hT[tx * 4 + c][ty * 4 + r] = h1v[r][c];
    // ---- phase B: FFN GEMMs (Hc aliases bufA) ----
    const float4* W14 = (const float4*)fW1;
    const float4* W24 = (const float4*)fW2;
    float outv[4][4];
    {
        float4 bb = ((const float4*)fb2)[tx];
#pragma unroll
        for (int r = 0; r < 4; r++) { outv[r][0] = bb.x; outv[r][1] = bb.y; outv[r][2] = bb.z; outv[r][3] = bb.w; }
    }
    __syncthreads();   // hT ready; all aoT reads done -> bufA reusable

    for (int tc = 0; tc < 4; ++tc) {
        float a2[4][4];
        {
            float4 bb1 = ((const float4*)fb1)[tc * 16 + tx];
#pragma unroll
            for (int r = 0; r < 4; r++) { a2[r][0] = bb1.x; a2[r][1] = bb1.y; a2[r][2] = bb1.z; a2[r][3] = bb1.w; }
        }
#pragma unroll 4
        for (int j = 0; j < 64; ++j) {
            float4 a = *(const float4*)&hT[j][ty * 4];
            float4 w = W14[j * 64 + tc * 16 + tx];
            float ar[4] = {a.x, a.y, a.z, a.w}, wr[4] = {w.x, w.y, w.z, w.w};
#pragma unroll
            for (int r = 0; r < 4; r++)
#pragma unroll
                for (int c = 0; c < 4; c++) a2[r][c] += ar[r] * wr[c];
        }
        __syncthreads();   // prev Hc reads done
#pragma unroll
        for (int r = 0; r < 4; r++)
#pragma unroll
            for (int c = 0; c < 4; c++) bufA[tx * 4 + c][ty * 4 + r] = fmaxf(a2[r][c], 0.f);
        __syncthreads();
#pragma unroll 4
        for (int h = 0; h < 64; ++h) {
            float4 a = *(const float4*)&bufA[h][ty * 4];
            float4 w = W24[(tc * 64 + h) * 16 + tx];
            float ar[4] = {a.x, a.y, a.z, a.w}, wr[4] = {w.x, w.y, w.z, w.w};
#pragma unroll
            for (int r = 0; r < 4; r++)
#pragma unroll
                for (int c = 0; c < 4; c++) outv[r][c] += ar[r] * wr[c];
        }
    }
    // residual (h1v) + LN2 -> z
    {
        float4 gg = ((const float4*)g2)[tx], bb = ((const float4*)b2)[tx];
        float4* zp = (float4*)(ws + WS_H0 + (size_t)row0 * D_);
#pragma unroll
        for (int r = 0; r < 4; r++) {
            outv[r][0] += h1v[r][0]; outv[r][1] += h1v[r][1];
            outv[r][2] += h1v[r][2]; outv[r][3] += h1v[r][3];
            float s = outv[r][0] + outv[r][1] + outv[r][2] + outv[r][3];
            s += __shfl_xor(s, 1); s += __shfl_xor(s, 2); s += __shfl_xor(s, 4); s += __shfl_xor(s, 8);
            float mean_ = s * (1.f / 64.f);
            float vv = 0.f;
#pragma unroll
            for (int c = 0; c < 4; c++) { float d_ = outv[r][c] - mean_; vv += d_ * d_; }
            vv += __shfl_xor(vv, 1); vv += __shfl_xor(vv, 2); vv += __shfl_xor(vv, 4); vv += __shfl_xor(vv, 8);
            float rstd = 1.f / sqrtf(vv * (1.f / 64.f) + EPS_);
            float4 z;
            z.x = (outv[r][0] - mean_) * rstd * gg.x + bb.x;
            z.y = (outv[r][1] - mean_) * rstd * gg.y + bb.y;
            z.z = (outv[r][2] - mean_) * rstd * gg.z + bb.z;
            z.w = (outv[r][3] - mean_) * rstd * gg.w + bb.w;
            zp[(ty * 4 + r) * 16 + tx] = z;
        }
    }
}

// ---------------- quantizer: LDS-tiled register-blocked distance GEMM ----------------
#define QROWS 128
#define QKT   64
#define ZTS   132
#define CBS   68

__global__ __launch_bounds__(TPB) void k_quant(
    float* __restrict__ ws, const float* __restrict__ cb, float* __restrict__ out) {
    __shared__ float zT[64][ZTS];
    __shared__ float cbT[64][CBS];
    __shared__ float z2s[QROWS];
    __shared__ float e2t[QKT];
    __shared__ int   ridx[QROWS];
    __shared__ float red[TPB];

    const int tid = threadIdx.x;
    const int row0 = blockIdx.x * QROWS;
    const float* zg = ws + WS_H0 + (size_t)row0 * D_;
    const float4* zg4 = (const float4*)zg;
    const float4* cbg4 = (const float4*)cb;

    {
        int j4 = tid >> 4;
#pragma unroll
        for (int it = 0; it < 8; ++it) {
            int r = (tid & 15) + it * 16;
            float4 v = zg4[r * 16 + j4];
            zT[j4 * 4 + 0][r] = v.x; zT[j4 * 4 + 1][r] = v.y;
            zT[j4 * 4 + 2][r] = v.z; zT[j4 * 4 + 3][r] = v.w;
        }
    }
    if (tid < QROWS) {
        const float4* zr = (const float4*)(zg + (size_t)tid * D_);
        float s = 0.f;
#pragma unroll
        for (int j = 0; j < 16; j++) { float4 v = zr[j]; s += v.x * v.x + v.y * v.y + v.z * v.z + v.w * v.w; }
        z2s[tid] = s;
    }

    const int ty = tid >> 4, tx = tid & 15;
    float best[8]; int bidx[8];
#pragma unroll
    for (int u = 0; u < 8; u++) { best[u] = 3.4e38f; bidx[u] = 0; }

    for (int t = 0; t < K_ / QKT; ++t) {
        const int k0 = t * QKT;
        __syncthreads();
        {
            int j4 = tid >> 4;
#pragma unroll
            for (int it = 0; it < 4; ++it) {
                int kk = (tid & 15) + it * 16;
                float4 v = cbg4[(size_t)(k0 + kk) * 16 + j4];
                cbT[j4 * 4 + 0][kk] = v.x; cbT[j4 * 4 + 1][kk] = v.y;
                cbT[j4 * 4 + 2][kk] = v.z; cbT[j4 * 4 + 3][kk] = v.w;
            }
        }
        if (tid < QKT) e2t[tid] = ws[WS_E2 + k0 + tid];
        __syncthreads();

        float acc[8][4];
#pragma unroll
        for (int u = 0; u < 8; u++)
#pragma unroll
            for (int c = 0; c < 4; c++) acc[u][c] = 0.f;

        for (int j = 0; j < 64; ++j) {
            float4 a0 = *(const float4*)&zT[j][ty * 8];
            float4 a1 = *(const float4*)&zT[j][ty * 8 + 4];
            float4 b0 = *(const float4*)&cbT[j][tx * 4];
            float ar[8] = {a0.x, a0.y, a0.z, a0.w, a1.x, a1.y, a1.z, a1.w};
            float br[4] = {b0.x, b0.y, b0.z, b0.w};
#pragma unroll
            for (int u = 0; u < 8; u++)
#pragma unroll
                for (int c = 0; c < 4; c++) acc[u][c] += ar[u] * br[c];
        }

#pragma unroll
        for (int u = 0; u < 8; u++) {
            float z2v = z2s[ty * 8 + u];
#pragma unroll
            for (int c = 0; c < 4; c++) {
                float dist = (z2v + e2t[tx * 4 + c]) - 2.f * acc[u][c];
                int kidx = k0 + tx * 4 + c;
                if (dist < best[u]) { best[u] = dist; bidx[u] = kidx; }
            }
        }
    }

#pragma unroll
    for (int m = 1; m <= 8; m <<= 1) {
#pragma unroll
        for (int u = 0; u < 8; u++) {
            float ob = __shfl_xor(best[u], m, 64);
            int oi = __shfl_xor(bidx[u], m, 64);
            if (ob < best[u] || (ob == best[u] && oi < bidx[u])) { best[u] = ob; bidx[u] = oi; }
        }
    }
    if (tx == 0) {
#pragma unroll
        for (int u = 0; u < 8; u++) ridx[ty * 8 + u] = bidx[u];
    }
    __syncthreads();

    if (tid < QROWS) {
        int bi = ridx[tid];
        out[OUT_IDX + row0 + tid] = (float)bi;
        atomicAdd((unsigned int*)ws + WS_COUNTS + bi, 1u);
    }
    {
        int r = tid >> 1, half = tid & 1;
        int bi = ridx[r];
        const float4* cw = (const float4*)(cb + (size_t)bi * D_ + half * 32);
        const float4* zr4 = (const float4*)(zg + (size_t)r * D_ + half * 32);
        float2* zqo = (float2*)(out + OUT_ZQ + (size_t)(row0 + r) * D_ + half * 32);
        float csum = 0.f;
#pragma unroll
        for (int j4 = 0; j4 < 8; ++j4) {
            float4 w = cw[j4]; float4 zz = zr4[j4];
            float d0 = w.x - zz.x, d1 = w.y - zz.y, d2 = w.z - zz.z, d3 = w.w - zz.w;
            csum += d0 * d0 + d1 * d1 + d2 * d2 + d3 * d3;
            float2 p0; p0.x = w.x; p0.y = w.y; zqo[j4 * 2] = p0;
            float2 p1; p1.x = w.z; p1.y = w.w; zqo[j4 * 2 + 1] = p1;
        }
        red[tid] = csum;
    }
    __syncthreads();
    for (int o2 = 128; o2 > 0; o2 >>= 1) {
        if (tid < o2) red[tid] += red[tid + o2];
        __syncthreads();
    }
    if (tid == 0) ws[WS_CPART + blockIdx.x] = red[0];
}

// ---------------- decoder: LDS-tiled GEMM + LN + denorm + rec-loss ----------------
#define DR_ 64

__global__ __launch_bounds__(TPB) void k_dec(
    float* __restrict__ ws, const float* __restrict__ x, const float* __restrict__ cb,
    const float* __restrict__ dW1, const float* __restrict__ db1,
    const float* __restrict__ dW2, const float* __restrict__ db2,
    const float* __restrict__ dWr, const float* __restrict__ dbr,
    const float* __restrict__ lng, const float* __restrict__ lnb,
    const float* __restrict__ rw, const float* __restrict__ rb,
    float* __restrict__ out) {
    __shared__ float zqT[64][FHS];
    __shared__ float Hc[64][FHS];
    __shared__ int   ridx[DR_];
    __shared__ float red[TPB];
    const int tid = threadIdx.x;
    const int row0 = blockIdx.x * DR_;
    if (tid < DR_) ridx[tid] = (int)out[OUT_IDX + row0 + tid];
    __syncthreads();
    {
        const float4* cb4 = (const float4*)cb;
#pragma unroll
        for (int it = 0; it < 4; ++it) {
            int e = tid + it * 256;
            int r = e >> 4, j4 = e & 15;
            float4 v = cb4[(size_t)ridx[r] * 16 + j4];
            zqT[j4 * 4 + 0][r] = v.x; zqT[j4 * 4 + 1][r] = v.y;
            zqT[j4 * 4 + 2][r] = v.z; zqT[j4 * 4 + 3][r] = v.w;
        }
    }
    const int ty = tid >> 4, tx = tid & 15;
    const float4* dW14 = (const float4*)dW1;
    float out4[4];
    {
        float b0 = db2[tx] + dbr[tx];
#pragma unroll
        for (int r = 0; r < 4; r++) out4[r] = b0;
    }
    __syncthreads();

    for (int tc = 0; tc < 4; ++tc) {
        float acc[4][4];
        {
            float4 bb1 = ((const float4*)db1)[tc * 16 + tx];
#pragma unroll
            for (int r = 0; r < 4; r++) { acc[r][0] = bb1.x; acc[r][1] = bb1.y; acc[r][2] = bb1.z; acc[r][3] = bb1.w; }
        }
#pragma unroll 4
        for (int j = 0; j < 64; ++j) {
            float4 a = *(const float4*)&zqT[j][ty * 4];
            float4 w = dW14[j * 64 + tc * 16 + tx];
            float ar[4] = {a.x, a.y, a.z, a.w}, wr[4] = {w.x, w.y, w.z, w.w};
#pragma unroll
            for (int r = 0; r < 4; r++)
#pragma unroll
                for (int c = 0; c < 4; c++) acc[r][c] += ar[r] * wr[c];
        }
        __syncthreads();
#pragma unroll
        for (int r = 0; r < 4; r++)
#pragma unroll
            for (int c = 0; c < 4; c++) Hc[tx * 4 + c][ty * 4 + r] = fmaxf(acc[r][c], 0.f);
        __syncthreads();
#pragma unroll 8
        for (int h = 0; h < 64; ++h) {
            float4 a = *(const float4*)&Hc[h][ty * 4];
            float w = dW2[(tc * 64 + h) * 16 + tx];
            out4[0] += a.x * w; out4[1] += a.y * w; out4[2] += a.z * w; out4[3] += a.w * w;
        }
    }
#pragma unroll 8
    for (int j = 0; j < 64; ++j) {
        float4 a = *(const float4*)&zqT[j][ty * 4];
        float w = dWr[j * 16 + tx];
        out4[0] += a.x * w; out4[1] += a.y * w; out4[2] += a.z * w; out4[3] += a.w * w;
    }
    const int n = row0 >> 7;
    const int b = n >> 5, c = n & 31;
    const float sd = ws[WS_STD + n], mn = ws[WS_MEAN + n];
    const float inv = 1.f / (rw[c] + EPS_ * EPS_);
    const float rbc = rb[c];
    const float lg = lng[tx], lb = lnb[tx];
    float part = 0.f;
#pragma unroll
    for (int r = 0; r < 4; r++) {
        float v = out4[r];
        float s = v;
        s += __shfl_xor(s, 1); s += __shfl_xor(s, 2); s += __shfl_xor(s, 4); s += __shfl_xor(s, 8);
        float mean_ = s * (1.f / 16.f);
        float d_ = v - mean_;
        float vv = d_ * d_;
        vv += __shfl_xor(vv, 1); vv += __shfl_xor(vv, 2); vv += __shfl_xor(vv, 4); vv += __shfl_xor(vv, 8);
        float rstd = 1.f / sqrtf(vv * (1.f / 16.f) + EPS_);
        float yv = d_ * rstd * lg + lb;
        float rr = (yv - rbc) * inv * sd + mn;
        int row = row0 + ty * 4 + r;
        int p = row & 127;
        size_t xi = (size_t)b * L_ * C_ + (size_t)(p * PL_ + tx) * C_ + c;
        out[OUT_R + xi] = rr;
        float dx = x[xi] - rr; part += dx * dx;
    }
    red[tid] = part;
    __syncthreads();
    for (int o2 = 128; o2 > 0; o2 >>= 1) {
        if (tid < o2) red[tid] += red[tid + o2];
        __syncthreads();
    }
    if (tid == 0) ws[WS_RPART + blockIdx.x] = red[0];
}

// ---------------- final scalar reductions ----------------
__global__ void k_final(float* __restrict__ ws, float* __restrict__ out) {
    __shared__ float sh[TPB];
    int tid = threadIdx.x;
    float cs = 0.f;
    for (int i2 = tid; i2 < 1024; i2 += TPB) cs += ws[WS_CPART + i2];
    sh[tid] = cs; __syncthreads();
    for (int o2 = 128; o2 > 0; o2 >>= 1) { if (tid < o2) sh[tid] += sh[tid + o2]; __syncthreads(); }
    float csum = sh[0]; __syncthreads();
    float rs = 0.f;
    for (int i2 = tid; i2 < 2048; i2 += TPB) rs += ws[WS_RPART + i2];
    sh[tid] = rs; __syncthreads();
    for (int o2 = 128; o2 > 0; o2 >>= 1) { if (tid < o2) sh[tid] += sh[tid + o2]; __syncthreads(); }
    float rsum = sh[0]; __syncthreads();
    const unsigned int* counts = (const unsigned int*)ws + WS_COUNTS;
    float H = 0.f;
    for (int k2 = tid; k2 < K_; k2 += TPB) {
        float p = (float)counts[k2] / (131072.f + EPS_);
        H += p * logf(p + EPS_);
    }
    sh[tid] = H; __syncthreads();
    for (int o2 = 128; o2 > 0; o2 >>= 1) { if (tid < o2) sh[tid] += sh[tid + o2]; __syncthreads(); }
    if (tid == 0) {
        float rec = rsum / 2097152.f;
        float msd = csum / 8388608.f;
        float cl = (1.f + BETA_) * msd;
        out[OUT_LOSS] = rec + CW_ * cl;
        out[OUT_REC] = rec;
        out[OUT_PERP] = expf(-sh[0]);
    }
}

extern "C" void kernel_launch(void* const* d_in, const int* in_sizes, int n_in,
                              void* d_out, int out_size, void* d_ws, size_t ws_size,
                              hipStream_t stream) {
    const float* x    = (const float*)d_in[0];
    const float* rw   = (const float*)d_in[1];
    const float* rb   = (const float*)d_in[2];
    const float* inpW = (const float*)d_in[3];
    const float* inpb = (const float*)d_in[4];
    const float* Wq   = (const float*)d_in[5];
    const float* bq   = (const float*)d_in[6];
    const float* Wk   = (const float*)d_in[7];
    const float* bk   = (const float*)d_in[8];
    const float* Wv   = (const float*)d_in[9];
    const float* bv   = (const float*)d_in[10];
    const float* Wo   = (const float*)d_in[11];
    const float* bo   = (const float*)d_in[12];
    const float* g1   = (const float*)d_in[13];
    const float* b1   = (const float*)d_in[14];
    const float* fW1  = (const float*)d_in[15];
    const float* fb1  = (const float*)d_in[16];
    const float* fW2  = (const float*)d_in[17];
    const float* fb2  = (const float*)d_in[18];
    const float* g2   = (const float*)d_in[19];
    const float* b2   = (const float*)d_in[20];
    const float* cb   = (const float*)d_in[21];
    const float* dW1  = (const float*)d_in[22];
    const float* db1  = (const float*)d_in[23];
    const float* dW2  = (const float*)d_in[24];
    const float* db2  = (const float*)d_in[25];
    const float* dWr  = (const float*)d_in[26];
    const float* dbr  = (const float*)d_in[27];
    const float* lng  = (const float*)d_in[28];
    const float* lnb  = (const float*)d_in[29];
    float* ws  = (float*)d_ws;
    float* out = (float*)d_out;

    hipMemsetAsync((char*)d_ws + (size_t)WS_COUNTS * 4, 0, 512 * 4, stream);
    k_prep<<<48, TPB, 0, stream>>>(Wq, Wk, Wv, cb, ws);
    k_stats<<<256, TPB, 0, stream>>>(x, ws);
    k_embed<<<(M_ * 16) / TPB, TPB, 0, stream>>>(x, rw, rb, inpW, inpb, ws);
    k_attn<<<N_ * 4, TPB, 0, stream>>>(ws, bq, bk, bv);
    k_woffn<<<M_ / 64, TPB, 0, stream>>>(ws, Wo, bo, g1, b1, fW1, fb1, fW2, fb2, g2, b2);
    k_quant<<<M_ / QROWS, TPB, 0, stream>>>(ws, cb, out);
    k_dec<<<M_ / DR_, TPB, 0, stream>>>(ws, x, cb, dW1, db1, dW2, db2, dWr, dbr, lng, lnb, rw, rb, out);
    k_final<<<1, TPB, 0, stream>>>(ws, out);
}